// Round 8
// baseline (292.021 us; speedup 1.0000x reference)
//
#include <hip/hip_runtime.h>
#include <math.h>

#define E_DIM 768
#define S_LEN 1024
#define B_SZ 2
#define H_CNT 12
#define D_HEAD 64
#define M_DIM 768
#define Q_STRIDE 4
#define N_FC1 771            // only M+Q-1 columns of fc1 are consumed
#define LD_H1 772            // padded col count for fc1 partials

typedef __attribute__((ext_vector_type(8))) short bf16x8;
typedef __attribute__((ext_vector_type(4))) float f32x4;

#define AS1 __attribute__((address_space(1)))
#define AS3 __attribute__((address_space(3)))

__device__ __forceinline__ void gld_lds16(void* lds, const void* g) {
    __builtin_amdgcn_global_load_lds((const AS1 void*)g, (AS3 void*)lds, 16, 0, 0);
}

__device__ __forceinline__ short f2bf(float f) {
    unsigned u = __float_as_uint(f);
    unsigned r = (u + 0x7fffu + ((u >> 16) & 1u)) >> 16;
    return (short)r;
}

__device__ __forceinline__ float bf2f(short s) {
    return __uint_as_float(((unsigned)(unsigned short)s) << 16);
}

// ---------------- block reduction helper (256 threads, 4 waves) ------------

__device__ __forceinline__ float block_reduce_sum(float v, volatile float* red) {
#pragma unroll
    for (int off = 32; off > 0; off >>= 1) v += __shfl_xor(v, off);
    __syncthreads();
    if ((threadIdx.x & 63) == 0) red[threadIdx.x >> 6] = v;
    __syncthreads();
    return red[0] + red[1] + red[2] + red[3];
}

// ---------------- weight fp32 -> bf16 conversion ---------------------------

__global__ __launch_bounds__(256) void convert_weights(
        const float* __restrict__ Wq, const float* __restrict__ Wk,
        const float* __restrict__ Wv, const float* __restrict__ Wo,
        const float* __restrict__ fc1W, const float* __restrict__ vqcW,
        const float* __restrict__ fc2W, short* __restrict__ dst) {
    int t = blockIdx.x * 256 + threadIdx.x;       // float4 index
    if (t >= 1475136) return;                     // 5900544 / 4
    int e = t * 4;
    const float* src; int off;
    if      (e < 589824)  { src = Wq;   off = e; }
    else if (e < 1179648) { src = Wk;   off = e - 589824; }
    else if (e < 1769472) { src = Wv;   off = e - 1179648; }
    else if (e < 2359296) { src = Wo;   off = e - 1769472; }
    else if (e < 2951424) { src = fc1W; off = e - 2359296; }
    else if (e < 3541248) { src = vqcW; off = e - 2951424; }
    else                  { src = fc2W; off = e - 3541248; }
    float4 v = *(const float4*)(src + off);
    short4 o = make_short4(f2bf(v.x), f2bf(v.y), f2bf(v.z), f2bf(v.w));
    *(short4*)(dst + e) = o;
}

__global__ void concat_bias(const float* __restrict__ bq, const float* __restrict__ bk,
                            const float* __restrict__ bv, float* __restrict__ bqkv) {
    int i = blockIdx.x * 256 + threadIdx.x;
    if (i >= 2304) return;
    float v = (i < 768) ? bq[i] : (i < 1536) ? bk[i - 768] : bv[i - 1536];
    bqkv[i] = v;
}

// ---------------- LayerNorm: one block per row, E=768, bf16 out ------------

__global__ __launch_bounds__(256) void ln_kernel(const float* __restrict__ x,
                                                 const float* __restrict__ w,
                                                 const float* __restrict__ b,
                                                 short* __restrict__ out) {
    __shared__ float red[4];
    int row = blockIdx.x;
    int tid = threadIdx.x;
    const float* xr = x + (size_t)row * E_DIM;
    float v0 = xr[tid], v1 = xr[tid + 256], v2 = xr[tid + 512];
    float s = block_reduce_sum(v0 + v1 + v2, red);
    float mu = s * (1.0f / E_DIM);
    float d0 = v0 - mu, d1 = v1 - mu, d2 = v2 - mu;
    float var = block_reduce_sum(d0 * d0 + d1 * d1 + d2 * d2, red) * (1.0f / E_DIM);
    float rs = rsqrtf(var + 1e-5f);
    short* orow = out + (size_t)row * E_DIM;
    orow[tid]       = f2bf(d0 * rs * w[tid]       + b[tid]);
    orow[tid + 256] = f2bf(d1 * rs * w[tid + 256] + b[tid + 256]);
    orow[tid + 512] = f2bf(d2 * rs * w[tid + 512] + b[tid + 512]);
}

// ---------------- k row norms from frag-major Kf ---------------------------

__global__ __launch_bounds__(256) void knorm2(const short* __restrict__ Kf,
                                              float* __restrict__ kn) {
    int idx = blockIdx.x * 256 + threadIdx.x;   // bh*1024 + s
    int s = idx & 1023, bh = idx >> 10;
    int jt = s >> 4, ml = s & 15;
    const short* base = Kf + (size_t)(bh * 64 + jt) * 1024 + ml * 8;
    float sum = 0.f;
#pragma unroll
    for (int c = 0; c < 2; c++)
#pragma unroll
        for (int kq = 0; kq < 4; kq++) {
            const short* p = base + c * 512 + kq * 128;
#pragma unroll
            for (int e = 0; e < 8; e++) { float v = bf2f(p[e]); sum += v * v; }
        }
    kn[idx] = sum;
}

// ---------------- bf16 MFMA NT GEMM (single-buffer, partial-only epilogue) -
// 128x128 tile, BK=32, 256 threads (4 waves 2x2), global_load_lds width 16.
// LDS k-slot XOR swizzle (slot = k ^ ((m>>1)&3)) -> 2-way bank aliasing (free).
// Split-K via blockIdx.z: block covers K range [z*klen, (z+1)*klen).
// ALL invocations write bf16 partials (no bias/activation) at
// outp[z*spitch + r*ldo + c]; downstream reduce kernels do bias/GELU/scatter.
// (R5/R6 lesson: complex runtime-branch epilogues flip the allocator into a
// 68-VGPR accumulator-spill regime — keep this epilogue minimal and uniform.)

__global__ __launch_bounds__(256, 2) void gemm_bf16(
        const short* __restrict__ A, int lda,
        const short* __restrict__ W, int ldw,
        short* __restrict__ outp, int ldo, size_t spitch,
        int N, int klen) {
    __shared__ short At[128 * 32];
    __shared__ short Bt[128 * 32];
    const int tid = threadIdx.x;
    const int lane = tid & 63;
    const int wave = tid >> 6;
    const int wr = (wave >> 1) * 64;
    const int wc = (wave & 1) * 64;
    const int ml = lane & 15;
    const int kq = lane >> 4;
    const int row0 = blockIdx.y * 128;
    const int col0 = blockIdx.x * 128;
    const int kbase = blockIdx.z * klen;

    // staging: chunk c -> LDS shorts [c*8, c*8+8); logical (m=c>>2,
    // kslot=c&3); source k-chunk = kslot ^ ((m>>1)&3)  (XOR swizzle)
    const int c0 = tid, c1 = tid + 256;
    const int am0 = c0 >> 2, ak0 = (((c0 & 3) ^ ((am0 >> 1) & 3))) * 8;
    const int am1 = c1 >> 2, ak1 = (((c1 & 3) ^ ((am1 >> 1) & 3))) * 8;
    const short* Ag0 = A + (size_t)(row0 + am0) * lda + ak0 + kbase;
    const short* Ag1 = A + (size_t)(row0 + am1) * lda + ak1 + kbase;
    int wrow0 = col0 + am0; if (wrow0 > N - 1) wrow0 = N - 1;
    int wrow1 = col0 + am1; if (wrow1 > N - 1) wrow1 = N - 1;
    const short* Wg0 = W + (size_t)wrow0 * ldw + ak0 + kbase;
    const short* Wg1 = W + (size_t)wrow1 * ldw + ak1 + kbase;

    const int kxor = (kq ^ ((ml >> 1) & 3)) * 8;   // reader swizzle

    f32x4 zero = {0.f, 0.f, 0.f, 0.f};
    f32x4 acc[4][4];
#pragma unroll
    for (int i = 0; i < 4; i++)
#pragma unroll
        for (int j = 0; j < 4; j++) acc[i][j] = zero;

    for (int k0 = 0; k0 < klen; k0 += 32) {
        gld_lds16(At + c0 * 8, Ag0 + k0);
        gld_lds16(At + c1 * 8, Ag1 + k0);
        gld_lds16(Bt + c0 * 8, Wg0 + k0);
        gld_lds16(Bt + c1 * 8, Wg1 + k0);
        __syncthreads();
        bf16x8 af[4], bfr[4];
#pragma unroll
        for (int i = 0; i < 4; i++)
            af[i] = *(const bf16x8*)&At[(wr + i * 16 + ml) * 32 + kxor];
#pragma unroll
        for (int j = 0; j < 4; j++)
            bfr[j] = *(const bf16x8*)&Bt[(wc + j * 16 + ml) * 32 + kxor];
#pragma unroll
        for (int i = 0; i < 4; i++)
#pragma unroll
            for (int j = 0; j < 4; j++)
                acc[i][j] = __builtin_amdgcn_mfma_f32_16x16x32_bf16(af[i], bfr[j], acc[i][j], 0, 0, 0);
        __syncthreads();
    }

    // epilogue: C/D layout col = lane&15, row = (lane>>4)*4 + reg
    short* outz = outp + blockIdx.z * spitch;
#pragma unroll
    for (int i = 0; i < 4; i++) {
#pragma unroll
        for (int j = 0; j < 4; j++) {
#pragma unroll
            for (int rr = 0; rr < 4; rr++) {
                int r = row0 + wr + i * 16 + kq * 4 + rr;
                int c = col0 + wc + j * 16 + ml;
                if (c < N) outz[(size_t)r * ldo + c] = f2bf(acc[i][j][rr]);
            }
        }
    }
}

// ---------------- split-K reduce kernels -----------------------------------

// QKV partials (2, bf16 [2048][2304]) + bias -> Q row-major bf16,
// K/V frag-major bf16 (scatter layouts match attn_mfma's staging).
__global__ __launch_bounds__(256) void reduce_qkv(
        const short* __restrict__ part, const float* __restrict__ bqkv,
        short* __restrict__ Qb, short* __restrict__ Kf, short* __restrict__ Vf) {
    int r = blockIdx.x, tid = threadIdx.x;
    const size_t SP = (size_t)2048 * 2304;
    const short* p0 = part + (size_t)r * 2304;
    const short* p1 = p0 + SP;
    int s = r & 1023, bb = r >> 10;
#pragma unroll
    for (int u = 0; u < 9; u++) {
        int c = tid + u * 256;
        float v = bf2f(p0[c]) + bf2f(p1[c]) + bqkv[c];
        short o = f2bf(v);
        if (c < 768) {
            Qb[(size_t)r * 768 + c] = o;
        } else if (c < 1536) {
            int df = c - 768; int hh = df >> 6, d = df & 63;
            int bh2 = bb * 12 + hh;
            size_t idx = ((size_t)(bh2 * 64 + (s >> 4)) * 2 + (d >> 5)) * 512
                       + (size_t)((d >> 3) & 3) * 128 + (size_t)(s & 15) * 8 + (d & 7);
            Kf[idx] = o;
        } else {
            int df = c - 1536; int hh = df >> 6, d = df & 63;
            int bh2 = bb * 12 + hh;
            size_t idx = ((size_t)(bh2 * 32 + (s >> 5))) * 2048
                       + (size_t)(d >> 4) * 512 + (size_t)((s >> 3) & 3) * 128
                       + (size_t)(d & 15) * 8 + (s & 7);
            Vf[idx] = o;
        }
    }
}

// Wo partials (4, bf16) + bo + residual x -> x2 fp32, then LN(ln2) -> y bf16
__global__ __launch_bounds__(256) void reduce_wo_ln(
        const short* __restrict__ part, const float* __restrict__ bo,
        const float* __restrict__ x, const float* __restrict__ w,
        const float* __restrict__ bvec, float* __restrict__ x2,
        short* __restrict__ y) {
    __shared__ float red[4];
    int row = blockIdx.x, tid = threadIdx.x;
    const size_t SP = (size_t)2048 * 768;
    const short* pr = part + (size_t)row * 768;
    const float* xr = x + (size_t)row * 768;
    float* x2r = x2 + (size_t)row * 768;
    float v[3];
#pragma unroll
    for (int u = 0; u < 3; u++) {
        int c = tid + u * 256;
        float s = bo[c] + xr[c];
#pragma unroll
        for (int z = 0; z < 4; z++) s += bf2f(pr[z * SP + c]);
        v[u] = s; x2r[c] = s;
    }
    float s = block_reduce_sum(v[0] + v[1] + v[2], red);
    float mu = s * (1.0f / 768.f);
    float d0 = v[0] - mu, d1 = v[1] - mu, d2 = v[2] - mu;
    float var = block_reduce_sum(d0 * d0 + d1 * d1 + d2 * d2, red) * (1.0f / 768.f);
    float rs = rsqrtf(var + 1e-5f);
    short* orow = y + (size_t)row * 768;
    orow[tid]       = f2bf(d0 * rs * w[tid]       + bvec[tid]);
    orow[tid + 256] = f2bf(d1 * rs * w[tid + 256] + bvec[tid + 256]);
    orow[tid + 512] = f2bf(d2 * rs * w[tid + 512] + bvec[tid + 512]);
}

// fc1 partials (4, bf16 [2048][772]) + bias -> expanded overlapping slices
// Avqc[(r*4+q)][m] = h1[r][m+q]  (h1 never materialized)
__global__ __launch_bounds__(256) void reduce_fc1_expand(
        const short* __restrict__ part, const float* __restrict__ b,
        short* __restrict__ Avqc) {
    __shared__ float row[LD_H1];
    int r = blockIdx.x, tid = threadIdx.x;
    const size_t SP = (size_t)2048 * LD_H1;
    const short* pr = part + (size_t)r * LD_H1;
#pragma unroll
    for (int u = 0; u < 3; u++) {
        int c = tid + u * 256;
        float s = b[c];
#pragma unroll
        for (int z = 0; z < 4; z++) s += bf2f(pr[z * SP + c]);
        row[c] = s;
    }
    if (tid < 3) {
        int c = 768 + tid;
        float s = b[c];
#pragma unroll
        for (int z = 0; z < 4; z++) s += bf2f(pr[z * SP + c]);
        row[c] = s;
    }
    __syncthreads();
#pragma unroll
    for (int q = 0; q < 4; q++) {
        short* orow = Avqc + (size_t)(r * 4 + q) * 768;
#pragma unroll
        for (int u = 0; u < 3; u++) {
            int m = tid + u * 256;
            orow[m] = f2bf(row[m + q]);
        }
    }
}

// vqc partials (2, bf16 [8192][768]) + bias + GELU + transpose scatter -> g
__global__ __launch_bounds__(256) void reduce_vqc(
        const short* __restrict__ part, const float* __restrict__ b,
        short* __restrict__ g) {
    int t = blockIdx.x * 256 + threadIdx.x;     // 4-col group; 1,572,864 total
    int r = t / 192;
    int c = (t - r * 192) * 4;
    size_t off = (size_t)r * 768 + c;
    const size_t SP = (size_t)8192 * 768;
    short4 a0 = *(const short4*)(part + off);
    short4 a1 = *(const short4*)(part + SP + off);
    float4 bb = *(const float4*)(b + c);
    float vv[4];
    vv[0] = bf2f(a0.x) + bf2f(a1.x) + bb.x;
    vv[1] = bf2f(a0.y) + bf2f(a1.y) + bb.y;
    vv[2] = bf2f(a0.z) + bf2f(a1.z) + bb.z;
    vv[3] = bf2f(a0.w) + bf2f(a1.w) + bb.w;
    short* orow = g + (size_t)(r >> 2) * 3072 + (r & 3);
#pragma unroll
    for (int i = 0; i < 4; i++) {
        float v = vv[i];
        v = 0.5f * v * (1.0f + erff(v * 0.70710678118654752f));
        orow[(c + i) * 4] = f2bf(v);
    }
}

// fc2 partials (8, bf16) + bias + residual x2 -> out fp32
__global__ __launch_bounds__(256) void reduce_fc2(
        const short* __restrict__ part, const float* __restrict__ b,
        const float* __restrict__ x2, float* __restrict__ out) {
    int t = blockIdx.x * 256 + threadIdx.x;     // 4-elem group; 393216 total
    int row = t / 192;
    int c = (t - row * 192) * 4;
    size_t off = (size_t)row * 768 + c;
    const size_t SP = (size_t)2048 * 768;
    float4 bb = *(const float4*)(b + c);
    float4 xx = *(const float4*)(x2 + off);
    float o0 = bb.x + xx.x, o1 = bb.y + xx.y, o2 = bb.z + xx.z, o3 = bb.w + xx.w;
#pragma unroll
    for (int z = 0; z < 8; z++) {
        short4 v = *(const short4*)(part + z * SP + off);
        o0 += bf2f(v.x); o1 += bf2f(v.y); o2 += bf2f(v.z); o3 += bf2f(v.w);
    }
    float4 o = make_float4(o0, o1, o2, o3);
    *(float4*)(out + off) = o;
}

// ---------------- MFMA fused attention (single-buffer, R4-proven) ----------

__global__ __launch_bounds__(256) void attn_mfma(
        const short* __restrict__ Qb,    // [2048][768] bf16
        const short* __restrict__ Kf,    // frag-major
        const short* __restrict__ Vf,    // frag-major
        const float* __restrict__ kn,    // [24][1024]
        const float* __restrict__ pond,
        short* __restrict__ vals) {      // [2048][768] bf16
    __shared__ __align__(16) short Kt[4096];
    __shared__ __align__(16) short Vt[4096];
    __shared__ float knl[1024];
    __shared__ float qn_l[4][16];
    __shared__ float is_l[4][16];
    __shared__ __align__(16) short Pe[4 * 16 * 72];
    __shared__ __align__(16) short Pr[4 * 16 * 72];

    const int tid = threadIdx.x;
    const int lane = tid & 63;
    const int wave = tid >> 6;
    const int ml = lane & 15;
    const int kq = lane >> 4;
    const int qt = blockIdx.x, h = blockIdx.y, b = blockIdx.z;
    const int bh = b * H_CNT + h;

    for (int i = tid; i < 1024; i += 256) knl[i] = kn[bh * 1024 + i];

    const int qrow = b * S_LEN + qt * 64 + wave * 16 + ml;
    const short* qp = Qb + (size_t)qrow * 768 + h * 64 + kq * 8;
    bf16x8 aq0 = *(const bf16x8*)qp;
    bf16x8 aq1 = *(const bf16x8*)(qp + 32);

    float qn_part = 0.f;
#pragma unroll
    for (int e = 0; e < 8; e++) {
        float v0 = bf2f(aq0[e]), v1 = bf2f(aq1[e]);
        qn_part += v0 * v0 + v1 * v1;
    }
    qn_part += __shfl_xor(qn_part, 16);
    qn_part += __shfl_xor(qn_part, 32);
    if (kq == 0) {
        qn_l[wave][ml] = qn_part;
        float sig = fminf(fmaxf(qn_part, 1e-8f), 1e4f);
        is_l[wave][ml] = 1.0f / sig;
    }
    __syncthreads();

    float qn_r[4], is_r[4];
#pragma unroll
    for (int r = 0; r < 4; r++) {
        qn_r[r] = qn_l[wave][kq * 4 + r];
        is_r[r] = is_l[wave][kq * 4 + r];
    }

    f32x4 Oe[4], Or[4];
#pragma unroll
    for (int dt = 0; dt < 4; dt++) { Oe[dt] = {0.f,0.f,0.f,0.f}; Or[dt] = {0.f,0.f,0.f,0.f}; }
    float es_p[4] = {0.f,0.f,0.f,0.f}, rs_p[4] = {0.f,0.f,0.f,0.f};

    const short* KfB = Kf + (size_t)bh * 65536;
    const short* VfB = Vf + (size_t)bh * 65536;
    short* PeW = Pe + wave * 1152;
    short* PrW = Pr + wave * 1152;

    for (int t = 0; t < 16; t++) {
        __syncthreads();
        {
            const short* sk = KfB + t * 4096 + tid * 8;
            gld_lds16(Kt + tid * 8, sk);
            gld_lds16(Kt + 2048 + tid * 8, sk + 2048);
            const short* sv = VfB + t * 4096 + tid * 8;
            gld_lds16(Vt + tid * 8, sv);
            gld_lds16(Vt + 2048 + tid * 8, sv + 2048);
        }
        __syncthreads();

#pragma unroll
        for (int jtl = 0; jtl < 4; jtl++) {
            bf16x8 bk0 = *(const bf16x8*)&Kt[(jtl * 2 + 0) * 512 + lane * 8];
            bf16x8 bk1 = *(const bf16x8*)&Kt[(jtl * 2 + 1) * 512 + lane * 8];
            f32x4 c = {0.f,0.f,0.f,0.f};
            c = __builtin_amdgcn_mfma_f32_16x16x32_bf16(aq0, bk0, c, 0, 0, 0);
            c = __builtin_amdgcn_mfma_f32_16x16x32_bf16(aq1, bk1, c, 0, 0, 0);
            float knj = knl[t * 64 + jtl * 16 + ml];
#pragma unroll
            for (int r = 0; r < 4; r++) {
                float qk = c[r];
                float e = __expf(qk * 0.125f);
                float tt = (2.f * qk - qn_r[r] - knj) * is_r[r];
                float rb = fminf(__expf(tt), 1.0f);
                es_p[r] += e; rs_p[r] += rb;
                PeW[(kq * 4 + r) * 72 + jtl * 16 + ml] = f2bf(e);
                PrW[(kq * 4 + r) * 72 + jtl * 16 + ml] = f2bf(rb);
            }
        }
        __syncthreads();

#pragma unroll
        for (int jcl = 0; jcl < 2; jcl++) {
            bf16x8 pa_e = *(const bf16x8*)&PeW[ml * 72 + jcl * 32 + kq * 8];
            bf16x8 pa_r = *(const bf16x8*)&PrW[ml * 72 + jcl * 32 + kq * 8];
#pragma unroll
            for (int dt = 0; dt < 4; dt++) {
                bf16x8 bv = *(const bf16x8*)&Vt[(jcl * 4 + dt) * 512 + lane * 8];
                Oe[dt] = __builtin_amdgcn_mfma_f32_16x16x32_bf16(pa_e, bv, Oe[dt], 0, 0, 0);
                Or[dt] = __builtin_amdgcn_mfma_f32_16x16x32_bf16(pa_r, bv, Or[dt], 0, 0, 0);
            }
        }
    }

#pragma unroll
    for (int off = 1; off <= 8; off <<= 1) {
#pragma unroll
        for (int r = 0; r < 4; r++) {
            es_p[r] += __shfl_xor(es_p[r], off);
            rs_p[r] += __shfl_xor(rs_p[r], off);
        }
    }

    float p = pond[0];
    float sv = 1.0f / (1.0f + __expf(-p));
    float p0 = 1.0f - sv, p1 = sv;
    float blendinv = 1.0f / (p0 + p1 + 1e-7f);
    float we[4], wr[4];
#pragma unroll
    for (int r = 0; r < 4; r++) {
        we[r] = p0 * blendinv / es_p[r];
        wr[r] = p1 * blendinv / fmaxf(rs_p[r], 1e-8f);
    }

#pragma unroll
    for (int dt = 0; dt < 4; dt++) {
#pragma unroll
        for (int r = 0; r < 4; r++) {
            float v = Oe[dt][r] * we[r] + Or[dt][r] * wr[r];
            int token = b * S_LEN + qt * 64 + wave * 16 + kq * 4 + r;
            vals[(size_t)token * 768 + h * 64 + dt * 16 + ml] = f2bf(v);
        }
    }
}

// ---------------- launcher -------------------------------------------------

extern "C" void kernel_launch(void* const* d_in, const int* in_sizes, int n_in,
                              void* d_out, int out_size, void* d_ws, size_t ws_size,
                              hipStream_t stream) {
    const float* x     = (const float*)d_in[0];
    const float* ln1_w = (const float*)d_in[1];
    const float* ln1_b = (const float*)d_in[2];
    const float* Wq    = (const float*)d_in[3];
    const float* bq    = (const float*)d_in[4];
    const float* Wk    = (const float*)d_in[5];
    const float* bk    = (const float*)d_in[6];
    const float* Wv    = (const float*)d_in[7];
    const float* bv    = (const float*)d_in[8];
    const float* Wo    = (const float*)d_in[9];
    const float* bo    = (const float*)d_in[10];
    const float* pond  = (const float*)d_in[11];
    const float* ln2_w = (const float*)d_in[12];
    const float* ln2_b = (const float*)d_in[13];
    const float* fc1_W = (const float*)d_in[14];
    const float* fc1_b = (const float*)d_in[15];
    const float* vqc_W = (const float*)d_in[16];
    const float* vqc_b = (const float*)d_in[17];
    const float* fc2_W = (const float*)d_in[18];
    const float* fc2_b = (const float*)d_in[19];
    float* out = (float*)d_out;

    char* p = (char*)d_ws;
    short* Qb   = (short*)p;  p += (size_t)2048 * 768 * 2;
    short* Kfb  = (short*)p;  p += (size_t)2048 * 768 * 2;
    short* Vfb  = (short*)p;  p += (size_t)2048 * 768 * 2;
    float* x2   = (float*)p;  p += (size_t)2048 * 768 * 4;
    float* kn   = (float*)p;  p += (size_t)24576 * 4;
    float* bqkv = (float*)p;  p += 2304 * 4;
    short* actb = (short*)p;  p += (size_t)2048 * 768 * 2;
    short* g    = (short*)p;  p += (size_t)2048 * 3072 * 2;
    short* Avqc = (short*)p;  p += (size_t)8192 * 768 * 2;
    short* partb = (short*)p; p += (size_t)8 * 2048 * 768 * 2;   // split-K partials (25.2 MB)
    short* wreg = (short*)p;  p += (size_t)5900544 * 2;
    short* Wqkvb = wreg;
    short* Wob   = wreg + 1769472;
    short* fc1b  = wreg + 2359296;
    short* vqcb  = wreg + 2951424;
    short* fc2b  = wreg + 3541248;

    dim3 blk(256);

    convert_weights<<<5763, blk, 0, stream>>>(Wq, Wk, Wv, Wo, fc1_W, vqc_W, fc2_W, wreg);
    concat_bias<<<9, blk, 0, stream>>>(bq, bk, bv, bqkv);

    // 1. ln1 -> actb (bf16)
    ln_kernel<<<2048, blk, 0, stream>>>(x, ln1_w, ln1_b, actb);
    // 2. fused QKV projection, split-K x2 -> bf16 partials [2][2048][2304]
    gemm_bf16<<<dim3(18, 16, 2), blk, 0, stream>>>(actb, 768, Wqkvb, 768,
                                                   partb, 2304, (size_t)2048 * 2304, 2304, 384);
    // 3. reduce + bias -> Qb row-major, Kf/Vf frag-major
    reduce_qkv<<<2048, blk, 0, stream>>>(partb, bqkv, Qb, Kfb, Vfb);
    // 4. k norms from Kf
    knorm2<<<96, blk, 0, stream>>>(Kfb, kn);
    // 5. MFMA attention -> vals (actb, bf16)
    attn_mfma<<<dim3(16, 12, 2), blk, 0, stream>>>(Qb, Kfb, Vfb, kn, pond, actb);
    // 6. Wo split-K x4 -> bf16 partials
    gemm_bf16<<<dim3(6, 16, 4), blk, 0, stream>>>(actb, 768, Wob, 768,
                                                  partb, 768, (size_t)2048 * 768, 768, 192);
    // 7. reduce + bo + residual(x) -> x2 fp32, fused ln2 -> actb
    reduce_wo_ln<<<2048, blk, 0, stream>>>(partb, bo, x, ln2_w, ln2_b, x2, actb);
    // 8. fc1 split-K x4 (N=771) -> bf16 partials [4][2048][772]
    gemm_bf16<<<dim3(7, 16, 4), blk, 0, stream>>>(actb, 768, fc1b, 768,
                                                  partb, LD_H1, (size_t)2048 * LD_H1, N_FC1, 192);
    // 9. reduce + bias + expand overlapping slices -> Avqc [8192][768]
    reduce_fc1_expand<<<2048, blk, 0, stream>>>(partb, fc1_b, Avqc);
    // 10. vqc split-K x2 -> bf16 partials [2][8192][768]
    gemm_bf16<<<dim3(6, 64, 2), blk, 0, stream>>>(Avqc, 768, vqcb, 768,
                                                  partb, 768, (size_t)8192 * 768, 768, 384);
    // 11. reduce + bias + gelu + transpose scatter -> g bf16 [2048][3072]
    reduce_vqc<<<6144, blk, 0, stream>>>(partb, vqc_b, g);
    // 12. fc2 split-K x8 -> bf16 partials
    gemm_bf16<<<dim3(6, 16, 8), blk, 0, stream>>>(g, 3072, fc2b, 3072,
                                                  partb, 768, (size_t)2048 * 768, 768, 384);
    // 13. reduce + bias + residual(x2) -> out fp32
    reduce_fc2<<<1536, blk, 0, stream>>>(partb, fc2_b, x2, out);
}

// Round 9
// 268.222 us; speedup vs baseline: 1.0887x; 1.0887x over previous
//
#include <hip/hip_runtime.h>
#include <math.h>

#define E_DIM 768
#define S_LEN 1024
#define B_SZ 2
#define H_CNT 12
#define D_HEAD 64
#define M_DIM 768
#define Q_STRIDE 4
#define N_FC1 771            // only M+Q-1 columns of fc1 are consumed
#define LD_H1 772            // padded col count for fc1 partials

typedef __attribute__((ext_vector_type(8))) short bf16x8;
typedef __attribute__((ext_vector_type(4))) float f32x4;

#define AS1 __attribute__((address_space(1)))
#define AS3 __attribute__((address_space(3)))

__device__ __forceinline__ void gld_lds16(void* lds, const void* g) {
    __builtin_amdgcn_global_load_lds((const AS1 void*)g, (AS3 void*)lds, 16, 0, 0);
}

__device__ __forceinline__ short f2bf(float f) {
    unsigned u = __float_as_uint(f);
    unsigned r = (u + 0x7fffu + ((u >> 16) & 1u)) >> 16;
    return (short)r;
}

__device__ __forceinline__ float bf2f(short s) {
    return __uint_as_float(((unsigned)(unsigned short)s) << 16);
}

// ---------------- block reduction helper (256 threads, 4 waves) ------------

__device__ __forceinline__ float block_reduce_sum(float v, volatile float* red) {
#pragma unroll
    for (int off = 32; off > 0; off >>= 1) v += __shfl_xor(v, off);
    __syncthreads();
    if ((threadIdx.x & 63) == 0) red[threadIdx.x >> 6] = v;
    __syncthreads();
    return red[0] + red[1] + red[2] + red[3];
}

// ---------------- weight fp32 -> bf16 conversion (+ fused bias concat) -----

__global__ __launch_bounds__(256) void convert_weights(
        const float* __restrict__ Wq, const float* __restrict__ Wk,
        const float* __restrict__ Wv, const float* __restrict__ Wo,
        const float* __restrict__ fc1W, const float* __restrict__ vqcW,
        const float* __restrict__ fc2W, short* __restrict__ dst,
        const float* __restrict__ bq, const float* __restrict__ bk,
        const float* __restrict__ bv, float* __restrict__ bqkv) {
    if (blockIdx.x == 5763) {       // fused concat_bias
#pragma unroll
        for (int u = 0; u < 9; u++) {
            int i = threadIdx.x + u * 256;
            float v = (i < 768) ? bq[i] : (i < 1536) ? bk[i - 768] : bv[i - 1536];
            bqkv[i] = v;
        }
        return;
    }
    int t = blockIdx.x * 256 + threadIdx.x;       // float4 index
    if (t >= 1475136) return;                     // 5900544 / 4
    int e = t * 4;
    const float* src; int off;
    if      (e < 589824)  { src = Wq;   off = e; }
    else if (e < 1179648) { src = Wk;   off = e - 589824; }
    else if (e < 1769472) { src = Wv;   off = e - 1179648; }
    else if (e < 2359296) { src = Wo;   off = e - 1769472; }
    else if (e < 2951424) { src = fc1W; off = e - 2359296; }
    else if (e < 3541248) { src = vqcW; off = e - 2951424; }
    else                  { src = fc2W; off = e - 3541248; }
    float4 v = *(const float4*)(src + off);
    short4 o = make_short4(f2bf(v.x), f2bf(v.y), f2bf(v.z), f2bf(v.w));
    *(short4*)(dst + e) = o;
}

// ---------------- LayerNorm: one block per row, E=768, bf16 out ------------

__global__ __launch_bounds__(256) void ln_kernel(const float* __restrict__ x,
                                                 const float* __restrict__ w,
                                                 const float* __restrict__ b,
                                                 short* __restrict__ out) {
    __shared__ float red[4];
    int row = blockIdx.x;
    int tid = threadIdx.x;
    const float* xr = x + (size_t)row * E_DIM;
    float v0 = xr[tid], v1 = xr[tid + 256], v2 = xr[tid + 512];
    float s = block_reduce_sum(v0 + v1 + v2, red);
    float mu = s * (1.0f / E_DIM);
    float d0 = v0 - mu, d1 = v1 - mu, d2 = v2 - mu;
    float var = block_reduce_sum(d0 * d0 + d1 * d1 + d2 * d2, red) * (1.0f / E_DIM);
    float rs = rsqrtf(var + 1e-5f);
    short* orow = out + (size_t)row * E_DIM;
    orow[tid]       = f2bf(d0 * rs * w[tid]       + b[tid]);
    orow[tid + 256] = f2bf(d1 * rs * w[tid + 256] + b[tid + 256]);
    orow[tid + 512] = f2bf(d2 * rs * w[tid + 512] + b[tid + 512]);
}

// ---------------- k row norms from frag-major Kf ---------------------------

__global__ __launch_bounds__(256) void knorm2(const short* __restrict__ Kf,
                                              float* __restrict__ kn) {
    int idx = blockIdx.x * 256 + threadIdx.x;   // bh*1024 + s
    int s = idx & 1023, bh = idx >> 10;
    int jt = s >> 4, ml = s & 15;
    const short* base = Kf + (size_t)(bh * 64 + jt) * 1024 + ml * 8;
    float sum = 0.f;
#pragma unroll
    for (int c = 0; c < 2; c++)
#pragma unroll
        for (int kq = 0; kq < 4; kq++) {
            const short* p = base + c * 512 + kq * 128;
#pragma unroll
            for (int e = 0; e < 8; e++) { float v = bf2f(p[e]); sum += v * v; }
        }
    kn[idx] = sum;
}

// ---------------- bf16 MFMA NT GEMM (BK=64, templated epilogue) ------------
// 128x128 tile, BK=64 (two 128x32 sub-slabs staged per barrier pair — halves
// barrier count vs BK=32; 32 KB LDS keeps >=4 blocks/CU capacity, unlike
// R5's failed BK=128/64KB). 256 threads (4 waves 2x2), global_load_lds w=16.
// LDS k-slot XOR swizzle (slot = k ^ ((m>>1)&3)) -> 2-way bank alias (free).
// Split-K via blockIdx.z: block covers K range [z*klen, (z+1)*klen).
// OUTMODE template (R5/R6 lesson: runtime-branch epilogues flip the register
// allocator into a 68-VGPR accumulator-spill regime; templates + (256,2) fix):
//   2 = bias + GELU + bf16 transpose-scatter (vqc)
//   3 = QKV split: bias; Q row-major, K/V frag-major scatter
//   5 = bf16 partial (no bias) at outp + z*spitch

template <int OUTMODE>
__global__ __launch_bounds__(256, 2) void gemm_bf16(
        const short* __restrict__ A, int lda,
        const short* __restrict__ W, int ldw,
        const float* __restrict__ bias,
        void* __restrict__ outp, int ldo, size_t spitch,
        short* __restrict__ Kfp, short* __restrict__ Vfp,
        int N, int klen, int dogelu) {
    __shared__ short At[2 * 4096];
    __shared__ short Bt[2 * 4096];
    const int tid = threadIdx.x;
    const int lane = tid & 63;
    const int wave = tid >> 6;
    const int wr = (wave >> 1) * 64;
    const int wc = (wave & 1) * 64;
    const int ml = lane & 15;
    const int kq = lane >> 4;
    const int row0 = blockIdx.y * 128;
    const int col0 = blockIdx.x * 128;
    const int kbase = blockIdx.z * klen;

    // staging: chunk c -> LDS shorts [c*8, c*8+8); logical (m=c>>2,
    // kslot=c&3); source k-chunk = kslot ^ ((m>>1)&3)  (XOR swizzle)
    const int c0 = tid, c1 = tid + 256;
    const int am0 = c0 >> 2, ak0 = (((c0 & 3) ^ ((am0 >> 1) & 3))) * 8;
    const int am1 = c1 >> 2, ak1 = (((c1 & 3) ^ ((am1 >> 1) & 3))) * 8;
    const short* Ag0 = A + (size_t)(row0 + am0) * lda + ak0 + kbase;
    const short* Ag1 = A + (size_t)(row0 + am1) * lda + ak1 + kbase;
    int wrow0 = col0 + am0; if (wrow0 > N - 1) wrow0 = N - 1;
    int wrow1 = col0 + am1; if (wrow1 > N - 1) wrow1 = N - 1;
    const short* Wg0 = W + (size_t)wrow0 * ldw + ak0 + kbase;
    const short* Wg1 = W + (size_t)wrow1 * ldw + ak1 + kbase;

    const int kxor = (kq ^ ((ml >> 1) & 3)) * 8;   // reader swizzle

    f32x4 zero = {0.f, 0.f, 0.f, 0.f};
    f32x4 acc[4][4];
#pragma unroll
    for (int i = 0; i < 4; i++)
#pragma unroll
        for (int j = 0; j < 4; j++) acc[i][j] = zero;

    for (int k0 = 0; k0 < klen; k0 += 64) {
        gld_lds16(At + c0 * 8, Ag0 + k0);
        gld_lds16(At + c1 * 8, Ag1 + k0);
        gld_lds16(At + 4096 + c0 * 8, Ag0 + k0 + 32);
        gld_lds16(At + 4096 + c1 * 8, Ag1 + k0 + 32);
        gld_lds16(Bt + c0 * 8, Wg0 + k0);
        gld_lds16(Bt + c1 * 8, Wg1 + k0);
        gld_lds16(Bt + 4096 + c0 * 8, Wg0 + k0 + 32);
        gld_lds16(Bt + 4096 + c1 * 8, Wg1 + k0 + 32);
        __syncthreads();
#pragma unroll
        for (int half = 0; half < 2; half++) {
            const short* Ah = At + half * 4096;
            const short* Bh = Bt + half * 4096;
            bf16x8 af[4], bfr[4];
#pragma unroll
            for (int i = 0; i < 4; i++)
                af[i] = *(const bf16x8*)&Ah[(wr + i * 16 + ml) * 32 + kxor];
#pragma unroll
            for (int j = 0; j < 4; j++)
                bfr[j] = *(const bf16x8*)&Bh[(wc + j * 16 + ml) * 32 + kxor];
#pragma unroll
            for (int i = 0; i < 4; i++)
#pragma unroll
                for (int j = 0; j < 4; j++)
                    acc[i][j] = __builtin_amdgcn_mfma_f32_16x16x32_bf16(af[i], bfr[j], acc[i][j], 0, 0, 0);
        }
        __syncthreads();
    }

    // epilogue: C/D layout col = lane&15, row = (lane>>4)*4 + reg
#pragma unroll
    for (int i = 0; i < 4; i++) {
#pragma unroll
        for (int j = 0; j < 4; j++) {
#pragma unroll
            for (int rr = 0; rr < 4; rr++) {
                int r = row0 + wr + i * 16 + kq * 4 + rr;
                int c = col0 + wc + j * 16 + ml;
                if (c < N) {
                    float v = acc[i][j][rr];
                    if (OUTMODE < 4) v += bias[c];
                    if (OUTMODE == 2 && dogelu)
                        v = 0.5f * v * (1.0f + erff(v * 0.70710678118654752f));
                    if (OUTMODE == 2) {
                        ((short*)outp)[(size_t)(r >> 2) * ldo + c * 4 + (r & 3)] = f2bf(v);
                    } else if (OUTMODE == 5) {
                        ((short*)outp)[blockIdx.z * spitch + (size_t)r * ldo + c] = f2bf(v);
                    } else if (OUTMODE == 3) {
                        int s = r & 1023, bb = r >> 10;
                        if (c < 768) {
                            ((short*)outp)[(size_t)r * 768 + c] = f2bf(v);
                        } else if (c < 1536) {
                            int df = c - 768; int hh = df >> 6, d = df & 63;
                            int bh2 = bb * 12 + hh;
                            size_t idx = ((size_t)(bh2 * 64 + (s >> 4)) * 2 + (d >> 5)) * 512
                                       + (size_t)((d >> 3) & 3) * 128 + (size_t)(s & 15) * 8 + (d & 7);
                            Kfp[idx] = f2bf(v);
                        } else {
                            int df = c - 1536; int hh = df >> 6, d = df & 63;
                            int bh2 = bb * 12 + hh;
                            size_t idx = ((size_t)(bh2 * 32 + (s >> 5))) * 2048
                                       + (size_t)(d >> 4) * 512 + (size_t)((s >> 3) & 3) * 128
                                       + (size_t)(d & 15) * 8 + (s & 7);
                            Vfp[idx] = f2bf(v);
                        }
                    }
                }
            }
        }
    }
}

// ---------------- split-K reduce kernels -----------------------------------

// Wo partials (4, bf16) + bo + residual x -> x2 fp32, then LN(ln2) -> y bf16
__global__ __launch_bounds__(256) void reduce_wo_ln(
        const short* __restrict__ part, const float* __restrict__ bo,
        const float* __restrict__ x, const float* __restrict__ w,
        const float* __restrict__ bvec, float* __restrict__ x2,
        short* __restrict__ y) {
    __shared__ float red[4];
    int row = blockIdx.x, tid = threadIdx.x;
    const size_t SP = (size_t)2048 * 768;
    const short* pr = part + (size_t)row * 768;
    const float* xr = x + (size_t)row * 768;
    float* x2r = x2 + (size_t)row * 768;
    float v[3];
#pragma unroll
    for (int u = 0; u < 3; u++) {
        int c = tid + u * 256;
        float s = bo[c] + xr[c];
#pragma unroll
        for (int z = 0; z < 4; z++) s += bf2f(pr[z * SP + c]);
        v[u] = s; x2r[c] = s;
    }
    float s = block_reduce_sum(v[0] + v[1] + v[2], red);
    float mu = s * (1.0f / 768.f);
    float d0 = v[0] - mu, d1 = v[1] - mu, d2 = v[2] - mu;
    float var = block_reduce_sum(d0 * d0 + d1 * d1 + d2 * d2, red) * (1.0f / 768.f);
    float rs = rsqrtf(var + 1e-5f);
    short* orow = y + (size_t)row * 768;
    orow[tid]       = f2bf(d0 * rs * w[tid]       + bvec[tid]);
    orow[tid + 256] = f2bf(d1 * rs * w[tid + 256] + bvec[tid + 256]);
    orow[tid + 512] = f2bf(d2 * rs * w[tid + 512] + bvec[tid + 512]);
}

// fc1 partials (4, bf16 [2048][772]) + bias -> expanded overlapping slices
// Avqc[(r*4+q)][m] = h1[r][m+q]  (h1 never materialized)
__global__ __launch_bounds__(256) void reduce_fc1_expand(
        const short* __restrict__ part, const float* __restrict__ b,
        short* __restrict__ Avqc) {
    __shared__ float row[LD_H1];
    int r = blockIdx.x, tid = threadIdx.x;
    const size_t SP = (size_t)2048 * LD_H1;
    const short* pr = part + (size_t)r * LD_H1;
#pragma unroll
    for (int u = 0; u < 3; u++) {
        int c = tid + u * 256;
        float s = b[c];
#pragma unroll
        for (int z = 0; z < 4; z++) s += bf2f(pr[z * SP + c]);
        row[c] = s;
    }
    if (tid < 3) {
        int c = 768 + tid;
        float s = b[c];
#pragma unroll
        for (int z = 0; z < 4; z++) s += bf2f(pr[z * SP + c]);
        row[c] = s;
    }
    __syncthreads();
#pragma unroll
    for (int q = 0; q < 4; q++) {
        short* orow = Avqc + (size_t)(r * 4 + q) * 768;
#pragma unroll
        for (int u = 0; u < 3; u++) {
            int m = tid + u * 256;
            orow[m] = f2bf(row[m + q]);
        }
    }
}

// fc2 partials (8, bf16) + bias + residual x2 -> out fp32
__global__ __launch_bounds__(256) void reduce_fc2(
        const short* __restrict__ part, const float* __restrict__ b,
        const float* __restrict__ x2, float* __restrict__ out) {
    int t = blockIdx.x * 256 + threadIdx.x;     // 4-elem group; 393216 total
    int row = t / 192;
    int c = (t - row * 192) * 4;
    size_t off = (size_t)row * 768 + c;
    const size_t SP = (size_t)2048 * 768;
    float4 bb = *(const float4*)(b + c);
    float4 xx = *(const float4*)(x2 + off);
    float o0 = bb.x + xx.x, o1 = bb.y + xx.y, o2 = bb.z + xx.z, o3 = bb.w + xx.w;
#pragma unroll
    for (int z = 0; z < 8; z++) {
        short4 v = *(const short4*)(part + z * SP + off);
        o0 += bf2f(v.x); o1 += bf2f(v.y); o2 += bf2f(v.z); o3 += bf2f(v.w);
    }
    float4 o = make_float4(o0, o1, o2, o3);
    *(float4*)(out + off) = o;
}

// ---------------- MFMA fused attention (P-barrier removed) -----------------
// Pe/Pr are strictly per-wave LDS regions; wave-internal LDS ops execute in
// program order, so no __syncthreads is needed between P write and P read.

__global__ __launch_bounds__(256) void attn_mfma(
        const short* __restrict__ Qb,    // [2048][768] bf16
        const short* __restrict__ Kf,    // frag-major
        const short* __restrict__ Vf,    // frag-major
        const float* __restrict__ kn,    // [24][1024]
        const float* __restrict__ pond,
        short* __restrict__ vals) {      // [2048][768] bf16
    __shared__ __align__(16) short Kt[4096];
    __shared__ __align__(16) short Vt[4096];
    __shared__ float knl[1024];
    __shared__ float qn_l[4][16];
    __shared__ float is_l[4][16];
    __shared__ __align__(16) short Pe[4 * 16 * 72];
    __shared__ __align__(16) short Pr[4 * 16 * 72];

    const int tid = threadIdx.x;
    const int lane = tid & 63;
    const int wave = tid >> 6;
    const int ml = lane & 15;
    const int kq = lane >> 4;
    const int qt = blockIdx.x, h = blockIdx.y, b = blockIdx.z;
    const int bh = b * H_CNT + h;

    for (int i = tid; i < 1024; i += 256) knl[i] = kn[bh * 1024 + i];

    const int qrow = b * S_LEN + qt * 64 + wave * 16 + ml;
    const short* qp = Qb + (size_t)qrow * 768 + h * 64 + kq * 8;
    bf16x8 aq0 = *(const bf16x8*)qp;
    bf16x8 aq1 = *(const bf16x8*)(qp + 32);

    float qn_part = 0.f;
#pragma unroll
    for (int e = 0; e < 8; e++) {
        float v0 = bf2f(aq0[e]), v1 = bf2f(aq1[e]);
        qn_part += v0 * v0 + v1 * v1;
    }
    qn_part += __shfl_xor(qn_part, 16);
    qn_part += __shfl_xor(qn_part, 32);
    if (kq == 0) {
        qn_l[wave][ml] = qn_part;
        float sig = fminf(fmaxf(qn_part, 1e-8f), 1e4f);
        is_l[wave][ml] = 1.0f / sig;
    }
    __syncthreads();

    float qn_r[4], is_r[4];
#pragma unroll
    for (int r = 0; r < 4; r++) {
        qn_r[r] = qn_l[wave][kq * 4 + r];
        is_r[r] = is_l[wave][kq * 4 + r];
    }

    f32x4 Oe[4], Or[4];
#pragma unroll
    for (int dt = 0; dt < 4; dt++) { Oe[dt] = {0.f,0.f,0.f,0.f}; Or[dt] = {0.f,0.f,0.f,0.f}; }
    float es_p[4] = {0.f,0.f,0.f,0.f}, rs_p[4] = {0.f,0.f,0.f,0.f};

    const short* KfB = Kf + (size_t)bh * 65536;
    const short* VfB = Vf + (size_t)bh * 65536;
    short* PeW = Pe + wave * 1152;
    short* PrW = Pr + wave * 1152;

    for (int t = 0; t < 16; t++) {
        __syncthreads();   // all waves done reading prior Kt/Vt
        {
            const short* sk = KfB + t * 4096 + tid * 8;
            gld_lds16(Kt + tid * 8, sk);
            gld_lds16(Kt + 2048 + tid * 8, sk + 2048);
            const short* sv = VfB + t * 4096 + tid * 8;
            gld_lds16(Vt + tid * 8, sv);
            gld_lds16(Vt + 2048 + tid * 8, sv + 2048);
        }
        __syncthreads();   // tiles resident

#pragma unroll
        for (int jtl = 0; jtl < 4; jtl++) {
            bf16x8 bk0 = *(const bf16x8*)&Kt[(jtl * 2 + 0) * 512 + lane * 8];
            bf16x8 bk1 = *(const bf16x8*)&Kt[(jtl * 2 + 1) * 512 + lane * 8];
            f32x4 c = {0.f,0.f,0.f,0.f};
            c = __builtin_amdgcn_mfma_f32_16x16x32_bf16(aq0, bk0, c, 0, 0, 0);
            c = __builtin_amdgcn_mfma_f32_16x16x32_bf16(aq1, bk1, c, 0, 0, 0);
            float knj = knl[t * 64 + jtl * 16 + ml];
#pragma unroll
            for (int r = 0; r < 4; r++) {
                float qk = c[r];
                float e = __expf(qk * 0.125f);
                float tt = (2.f * qk - qn_r[r] - knj) * is_r[r];
                float rb = fminf(__expf(tt), 1.0f);
                es_p[r] += e; rs_p[r] += rb;
                PeW[(kq * 4 + r) * 72 + jtl * 16 + ml] = f2bf(e);
                PrW[(kq * 4 + r) * 72 + jtl * 16 + ml] = f2bf(rb);
            }
        }
        // (no barrier: P round-trip is wave-local)

#pragma unroll
        for (int jcl = 0; jcl < 2; jcl++) {
            bf16x8 pa_e = *(const bf16x8*)&PeW[ml * 72 + jcl * 32 + kq * 8];
            bf16x8 pa_r = *(const bf16x8*)&PrW[ml * 72 + jcl * 32 + kq * 8];
#pragma unroll
            for (int dt = 0; dt < 4; dt++) {
                bf16x8 bv = *(const bf16x8*)&Vt[(jcl * 4 + dt) * 512 + lane * 8];
                Oe[dt] = __builtin_amdgcn_mfma_f32_16x16x32_bf16(pa_e, bv, Oe[dt], 0, 0, 0);
                Or[dt] = __builtin_amdgcn_mfma_f32_16x16x32_bf16(pa_r, bv, Or[dt], 0, 0, 0);
            }
        }
    }

#pragma unroll
    for (int off = 1; off <= 8; off <<= 1) {
#pragma unroll
        for (int r = 0; r < 4; r++) {
            es_p[r] += __shfl_xor(es_p[r], off);
            rs_p[r] += __shfl_xor(rs_p[r], off);
        }
    }

    float p = pond[0];
    float sv = 1.0f / (1.0f + __expf(-p));
    float p0 = 1.0f - sv, p1 = sv;
    float blendinv = 1.0f / (p0 + p1 + 1e-7f);
    float we[4], wr[4];
#pragma unroll
    for (int r = 0; r < 4; r++) {
        we[r] = p0 * blendinv / es_p[r];
        wr[r] = p1 * blendinv / fmaxf(rs_p[r], 1e-8f);
    }

#pragma unroll
    for (int dt = 0; dt < 4; dt++) {
#pragma unroll
        for (int r = 0; r < 4; r++) {
            float v = Oe[dt][r] * we[r] + Or[dt][r] * wr[r];
            int token = b * S_LEN + qt * 64 + wave * 16 + kq * 4 + r;
            vals[(size_t)token * 768 + h * 64 + dt * 16 + ml] = f2bf(v);
        }
    }
}

// ---------------- launcher -------------------------------------------------

extern "C" void kernel_launch(void* const* d_in, const int* in_sizes, int n_in,
                              void* d_out, int out_size, void* d_ws, size_t ws_size,
                              hipStream_t stream) {
    const float* x     = (const float*)d_in[0];
    const float* ln1_w = (const float*)d_in[1];
    const float* ln1_b = (const float*)d_in[2];
    const float* Wq    = (const float*)d_in[3];
    const float* bq    = (const float*)d_in[4];
    const float* Wk    = (const float*)d_in[5];
    const float* bk    = (const float*)d_in[6];
    const float* Wv    = (const float*)d_in[7];
    const float* bv    = (const float*)d_in[8];
    const float* Wo    = (const float*)d_in[9];
    const float* bo    = (const float*)d_in[10];
    const float* pond  = (const float*)d_in[11];
    const float* ln2_w = (const float*)d_in[12];
    const float* ln2_b = (const float*)d_in[13];
    const float* fc1_W = (const float*)d_in[14];
    const float* fc1_b = (const float*)d_in[15];
    const float* vqc_W = (const float*)d_in[16];
    const float* vqc_b = (const float*)d_in[17];
    const float* fc2_W = (const float*)d_in[18];
    const float* fc2_b = (const float*)d_in[19];
    float* out = (float*)d_out;

    char* p = (char*)d_ws;
    short* Qb   = (short*)p;  p += (size_t)2048 * 768 * 2;
    short* Kfb  = (short*)p;  p += (size_t)2048 * 768 * 2;
    short* Vfb  = (short*)p;  p += (size_t)2048 * 768 * 2;
    float* x2   = (float*)p;  p += (size_t)2048 * 768 * 4;
    float* kn   = (float*)p;  p += (size_t)24576 * 4;
    float* bqkv = (float*)p;  p += 2304 * 4;
    short* actb = (short*)p;  p += (size_t)2048 * 768 * 2;
    short* g    = (short*)p;  p += (size_t)2048 * 3072 * 2;
    short* Avqc = (short*)p;  p += (size_t)8192 * 768 * 2;
    short* partb = (short*)p; p += (size_t)8 * 2048 * 768 * 2;   // split-K partials (25.2 MB)
    short* wreg = (short*)p;  p += (size_t)5900544 * 2;
    short* Wqkvb = wreg;
    short* Wob   = wreg + 1769472;
    short* fc1b  = wreg + 2359296;
    short* vqcb  = wreg + 2951424;
    short* fc2b  = wreg + 3541248;

    dim3 blk(256);

    // 0. weight conversion + fused bias concat
    convert_weights<<<5764, blk, 0, stream>>>(Wq, Wk, Wv, Wo, fc1_W, vqc_W, fc2_W, wreg,
                                              bq, bk, bv, bqkv);
    // 1. ln1 -> actb (bf16)
    ln_kernel<<<2048, blk, 0, stream>>>(x, ln1_w, ln1_b, actb);
    // 2. fused QKV projection (direct): Qb row-major, Kf/Vf frag-major
    gemm_bf16<3><<<dim3(18, 16, 1), blk, 0, stream>>>(actb, 768, Wqkvb, 768, bqkv,
                                                      Qb, 768, 0, Kfb, Vfb, 2304, 768, 0);
    // 3. k norms from Kf
    knorm2<<<96, blk, 0, stream>>>(Kfb, kn);
    // 4. MFMA attention -> vals (actb, bf16)
    attn_mfma<<<dim3(16, 12, 2), blk, 0, stream>>>(Qb, Kfb, Vfb, kn, pond, actb);
    // 5. Wo split-K x4 -> bf16 partials
    gemm_bf16<5><<<dim3(6, 16, 4), blk, 0, stream>>>(actb, 768, Wob, 768, nullptr,
                                                     partb, 768, (size_t)2048 * 768,
                                                     nullptr, nullptr, 768, 192, 0);
    // 6. reduce + bo + residual(x) -> x2 fp32, fused ln2 -> actb
    reduce_wo_ln<<<2048, blk, 0, stream>>>(partb, bo, x, ln2_w, ln2_b, x2, actb);
    // 7. fc1 split-K x4 (N=771) -> bf16 partials [4][2048][772]
    gemm_bf16<5><<<dim3(7, 16, 4), blk, 0, stream>>>(actb, 768, fc1b, 768, nullptr,
                                                     partb, LD_H1, (size_t)2048 * LD_H1,
                                                     nullptr, nullptr, N_FC1, 192, 0);
    // 8. reduce + bias + expand overlapping slices -> Avqc [8192][768]
    reduce_fc1_expand<<<2048, blk, 0, stream>>>(partb, fc1_b, Avqc);
    // 9. vqc (direct) + bias + gelu + transpose scatter -> g bf16 [2048][3072]
    gemm_bf16<2><<<dim3(6, 64, 1), blk, 0, stream>>>(Avqc, 768, vqcb, 768, vqc_b,
                                                     g, 3072, 0, nullptr, nullptr, 768, 768, 1);
    // 10. fc2 split-K x8 -> bf16 partials
    gemm_bf16<5><<<dim3(6, 16, 8), blk, 0, stream>>>(g, 3072, fc2b, 3072, nullptr,
                                                     partb, 768, (size_t)2048 * 768,
                                                     nullptr, nullptr, 768, 384, 0);
    // 11. reduce + bias + residual(x2) -> out fp32
    reduce_fc2<<<1536, blk, 0, stream>>>(partb, fc2_b, x2, out);
}

// Round 10
// 261.166 us; speedup vs baseline: 1.1181x; 1.0270x over previous
//
#include <hip/hip_runtime.h>
#include <math.h>

#define E_DIM 768
#define S_LEN 1024
#define B_SZ 2
#define H_CNT 12
#define D_HEAD 64
#define M_DIM 768
#define Q_STRIDE 4
#define N_FC1 771            // only M+Q-1 columns of fc1 are consumed
#define LD_H1 772            // padded col count for fc1 partials

typedef __attribute__((ext_vector_type(8))) short bf16x8;
typedef __attribute__((ext_vector_type(4))) float f32x4;

#define AS1 __attribute__((address_space(1)))
#define AS3 __attribute__((address_space(3)))

__device__ __forceinline__ void gld_lds16(void* lds, const void* g) {
    __builtin_amdgcn_global_load_lds((const AS1 void*)g, (AS3 void*)lds, 16, 0, 0);
}

__device__ __forceinline__ short f2bf(float f) {
    unsigned u = __float_as_uint(f);
    unsigned r = (u + 0x7fffu + ((u >> 16) & 1u)) >> 16;
    return (short)r;
}

__device__ __forceinline__ float bf2f(short s) {
    return __uint_as_float(((unsigned)(unsigned short)s) << 16);
}

// ---------------- block reduction helper (256 threads, 4 waves) ------------

__device__ __forceinline__ float block_reduce_sum(float v, volatile float* red) {
#pragma unroll
    for (int off = 32; off > 0; off >>= 1) v += __shfl_xor(v, off);
    __syncthreads();
    if ((threadIdx.x & 63) == 0) red[threadIdx.x >> 6] = v;
    __syncthreads();
    return red[0] + red[1] + red[2] + red[3];
}

// ---------------- weight fp32 -> bf16 conversion (+ fused bias concat) -----

__global__ __launch_bounds__(256) void convert_weights(
        const float* __restrict__ Wq, const float* __restrict__ Wk,
        const float* __restrict__ Wv, const float* __restrict__ Wo,
        const float* __restrict__ fc1W, const float* __restrict__ vqcW,
        const float* __restrict__ fc2W, short* __restrict__ dst,
        const float* __restrict__ bq, const float* __restrict__ bk,
        const float* __restrict__ bv, float* __restrict__ bqkv) {
    if (blockIdx.x == 5763) {       // fused concat_bias
#pragma unroll
        for (int u = 0; u < 9; u++) {
            int i = threadIdx.x + u * 256;
            float v = (i < 768) ? bq[i] : (i < 1536) ? bk[i - 768] : bv[i - 1536];
            bqkv[i] = v;
        }
        return;
    }
    int t = blockIdx.x * 256 + threadIdx.x;       // float4 index
    if (t >= 1475136) return;                     // 5900544 / 4
    int e = t * 4;
    const float* src; int off;
    if      (e < 589824)  { src = Wq;   off = e; }
    else if (e < 1179648) { src = Wk;   off = e - 589824; }
    else if (e < 1769472) { src = Wv;   off = e - 1179648; }
    else if (e < 2359296) { src = Wo;   off = e - 1769472; }
    else if (e < 2951424) { src = fc1W; off = e - 2359296; }
    else if (e < 3541248) { src = vqcW; off = e - 2951424; }
    else                  { src = fc2W; off = e - 3541248; }
    float4 v = *(const float4*)(src + off);
    short4 o = make_short4(f2bf(v.x), f2bf(v.y), f2bf(v.z), f2bf(v.w));
    *(short4*)(dst + e) = o;
}

// ---------------- LayerNorm: one block per row, E=768, bf16 out ------------

__global__ __launch_bounds__(256) void ln_kernel(const float* __restrict__ x,
                                                 const float* __restrict__ w,
                                                 const float* __restrict__ b,
                                                 short* __restrict__ out) {
    __shared__ float red[4];
    int row = blockIdx.x;
    int tid = threadIdx.x;
    const float* xr = x + (size_t)row * E_DIM;
    float v0 = xr[tid], v1 = xr[tid + 256], v2 = xr[tid + 512];
    float s = block_reduce_sum(v0 + v1 + v2, red);
    float mu = s * (1.0f / E_DIM);
    float d0 = v0 - mu, d1 = v1 - mu, d2 = v2 - mu;
    float var = block_reduce_sum(d0 * d0 + d1 * d1 + d2 * d2, red) * (1.0f / E_DIM);
    float rs = rsqrtf(var + 1e-5f);
    short* orow = out + (size_t)row * E_DIM;
    orow[tid]       = f2bf(d0 * rs * w[tid]       + b[tid]);
    orow[tid + 256] = f2bf(d1 * rs * w[tid + 256] + b[tid + 256]);
    orow[tid + 512] = f2bf(d2 * rs * w[tid + 512] + b[tid + 512]);
}

// ---------------- k row norms from frag-major Kf ---------------------------

__global__ __launch_bounds__(256) void knorm2(const short* __restrict__ Kf,
                                              float* __restrict__ kn) {
    int idx = blockIdx.x * 256 + threadIdx.x;   // bh*1024 + s
    int s = idx & 1023, bh = idx >> 10;
    int jt = s >> 4, ml = s & 15;
    const short* base = Kf + (size_t)(bh * 64 + jt) * 1024 + ml * 8;
    float sum = 0.f;
#pragma unroll
    for (int c = 0; c < 2; c++)
#pragma unroll
        for (int kq = 0; kq < 4; kq++) {
            const short* p = base + c * 512 + kq * 128;
#pragma unroll
            for (int e = 0; e < 8; e++) { float v = bf2f(p[e]); sum += v * v; }
        }
    kn[idx] = sum;
}

// ---------------- bf16 MFMA NT GEMM (BK=64, MR-templated tile height) ------
// MR x 128 tile (MR = 128 or 64), BK=64 as two MRx32 sub-slabs per barrier
// pair. 64-row tiles give exact 256-CU grid balance for the small GEMMs
// (R9 lesson: dispatch time quantizes to ceil(blocks/256) rounds — 288-block
// QKV wasted ~45% in a 32-CU tail). 256 threads (4 waves 2x2).
// LDS k-slot XOR swizzle (slot = k ^ ((m>>1)&3)) -> 2-way bank alias (free).
// Split-K via blockIdx.z. OUTMODE template (R5/R6 lesson: runtime-branch
// epilogues flip the allocator into a 68-VGPR accumulator-spill regime):
//   2 = bias + GELU + bf16 transpose-scatter (vqc)
//   3 = QKV split: bias; Q row-major, K/V frag-major scatter
//   5 = bf16 partial (no bias) at outp + z*spitch

template <int OUTMODE, int MR>
__global__ __launch_bounds__(256, 2) void gemm_bf16(
        const short* __restrict__ A, int lda,
        const short* __restrict__ W, int ldw,
        const float* __restrict__ bias,
        void* __restrict__ outp, int ldo, size_t spitch,
        short* __restrict__ Kfp, short* __restrict__ Vfp,
        int N, int klen, int dogelu) {
    constexpr int MI = MR / 32;          // A-frag / acc row count per wave
    constexpr int AH = MR * 32;          // shorts per A half-slab
    constexpr int NA = MR / 64;          // A chunks per thread per half
    __shared__ short At[2 * AH];
    __shared__ short Bt[2 * 4096];
    const int tid = threadIdx.x;
    const int lane = tid & 63;
    const int wave = tid >> 6;
    const int wr = (wave >> 1) * (MI * 16);
    const int wc = (wave & 1) * 64;
    const int ml = lane & 15;
    const int kq = lane >> 4;
    const int row0 = blockIdx.y * MR;
    const int col0 = blockIdx.x * 128;
    const int kbase = blockIdx.z * klen;

    // staging: chunk c covers LDS shorts [c*8,c*8+8) = (m=c>>2, kslot=c&3);
    // source k-chunk = kslot ^ ((m>>1)&3)  (XOR swizzle)
    const short* Ag[NA]; int aoff[NA];
#pragma unroll
    for (int u = 0; u < NA; u++) {
        int c = tid + u * 256;
        int am = c >> 2, ak = ((c & 3) ^ ((am >> 1) & 3)) * 8;
        Ag[u] = A + (size_t)(row0 + am) * lda + ak + kbase;
        aoff[u] = c * 8;
    }
    const int c0 = tid, c1 = tid + 256;
    const int bm0 = c0 >> 2, bk0 = (((c0 & 3) ^ ((bm0 >> 1) & 3))) * 8;
    const int bm1 = c1 >> 2, bk1 = (((c1 & 3) ^ ((bm1 >> 1) & 3))) * 8;
    int wrow0 = col0 + bm0; if (wrow0 > N - 1) wrow0 = N - 1;
    int wrow1 = col0 + bm1; if (wrow1 > N - 1) wrow1 = N - 1;
    const short* Wg0 = W + (size_t)wrow0 * ldw + bk0 + kbase;
    const short* Wg1 = W + (size_t)wrow1 * ldw + bk1 + kbase;

    const int kxor = (kq ^ ((ml >> 1) & 3)) * 8;   // reader swizzle

    f32x4 zero = {0.f, 0.f, 0.f, 0.f};
    f32x4 acc[MI][4];
#pragma unroll
    for (int i = 0; i < MI; i++)
#pragma unroll
        for (int j = 0; j < 4; j++) acc[i][j] = zero;

    for (int k0 = 0; k0 < klen; k0 += 64) {
#pragma unroll
        for (int u = 0; u < NA; u++) {
            gld_lds16(At + aoff[u], Ag[u] + k0);
            gld_lds16(At + AH + aoff[u], Ag[u] + k0 + 32);
        }
        gld_lds16(Bt + c0 * 8, Wg0 + k0);
        gld_lds16(Bt + c1 * 8, Wg1 + k0);
        gld_lds16(Bt + 4096 + c0 * 8, Wg0 + k0 + 32);
        gld_lds16(Bt + 4096 + c1 * 8, Wg1 + k0 + 32);
        __syncthreads();
#pragma unroll
        for (int half = 0; half < 2; half++) {
            const short* Ah = At + half * AH;
            const short* Bh = Bt + half * 4096;
            bf16x8 af[MI], bfr[4];
#pragma unroll
            for (int i = 0; i < MI; i++)
                af[i] = *(const bf16x8*)&Ah[(wr + i * 16 + ml) * 32 + kxor];
#pragma unroll
            for (int j = 0; j < 4; j++)
                bfr[j] = *(const bf16x8*)&Bh[(wc + j * 16 + ml) * 32 + kxor];
#pragma unroll
            for (int i = 0; i < MI; i++)
#pragma unroll
                for (int j = 0; j < 4; j++)
                    acc[i][j] = __builtin_amdgcn_mfma_f32_16x16x32_bf16(af[i], bfr[j], acc[i][j], 0, 0, 0);
        }
        __syncthreads();
    }

    // epilogue: C/D layout col = lane&15, row = (lane>>4)*4 + reg
#pragma unroll
    for (int i = 0; i < MI; i++) {
#pragma unroll
        for (int j = 0; j < 4; j++) {
#pragma unroll
            for (int rr = 0; rr < 4; rr++) {
                int r = row0 + wr + i * 16 + kq * 4 + rr;
                int c = col0 + wc + j * 16 + ml;
                if (c < N) {
                    float v = acc[i][j][rr];
                    if (OUTMODE < 4) v += bias[c];
                    if (OUTMODE == 2 && dogelu)
                        v = 0.5f * v * (1.0f + erff(v * 0.70710678118654752f));
                    if (OUTMODE == 2) {
                        ((short*)outp)[(size_t)(r >> 2) * ldo + c * 4 + (r & 3)] = f2bf(v);
                    } else if (OUTMODE == 5) {
                        ((short*)outp)[blockIdx.z * spitch + (size_t)r * ldo + c] = f2bf(v);
                    } else if (OUTMODE == 3) {
                        int s = r & 1023, bb = r >> 10;
                        if (c < 768) {
                            ((short*)outp)[(size_t)r * 768 + c] = f2bf(v);
                        } else if (c < 1536) {
                            int df = c - 768; int hh = df >> 6, d = df & 63;
                            int bh2 = bb * 12 + hh;
                            size_t idx = ((size_t)(bh2 * 64 + (s >> 4)) * 2 + (d >> 5)) * 512
                                       + (size_t)((d >> 3) & 3) * 128 + (size_t)(s & 15) * 8 + (d & 7);
                            Kfp[idx] = f2bf(v);
                        } else {
                            int df = c - 1536; int hh = df >> 6, d = df & 63;
                            int bh2 = bb * 12 + hh;
                            size_t idx = ((size_t)(bh2 * 32 + (s >> 5))) * 2048
                                       + (size_t)(d >> 4) * 512 + (size_t)((s >> 3) & 3) * 128
                                       + (size_t)(d & 15) * 8 + (s & 7);
                            Vfp[idx] = f2bf(v);
                        }
                    }
                }
            }
        }
    }
}

// ---------------- split-K reduce kernels -----------------------------------

// Wo partials (4, bf16) + bo + residual x -> x2 fp32, then LN(ln2) -> y bf16
__global__ __launch_bounds__(256) void reduce_wo_ln(
        const short* __restrict__ part, const float* __restrict__ bo,
        const float* __restrict__ x, const float* __restrict__ w,
        const float* __restrict__ bvec, float* __restrict__ x2,
        short* __restrict__ y) {
    __shared__ float red[4];
    int row = blockIdx.x, tid = threadIdx.x;
    const size_t SP = (size_t)2048 * 768;
    const short* pr = part + (size_t)row * 768;
    const float* xr = x + (size_t)row * 768;
    float* x2r = x2 + (size_t)row * 768;
    float v[3];
#pragma unroll
    for (int u = 0; u < 3; u++) {
        int c = tid + u * 256;
        float s = bo[c] + xr[c];
#pragma unroll
        for (int z = 0; z < 4; z++) s += bf2f(pr[z * SP + c]);
        v[u] = s; x2r[c] = s;
    }
    float s = block_reduce_sum(v[0] + v[1] + v[2], red);
    float mu = s * (1.0f / 768.f);
    float d0 = v[0] - mu, d1 = v[1] - mu, d2 = v[2] - mu;
    float var = block_reduce_sum(d0 * d0 + d1 * d1 + d2 * d2, red) * (1.0f / 768.f);
    float rs = rsqrtf(var + 1e-5f);
    short* orow = y + (size_t)row * 768;
    orow[tid]       = f2bf(d0 * rs * w[tid]       + bvec[tid]);
    orow[tid + 256] = f2bf(d1 * rs * w[tid + 256] + bvec[tid + 256]);
    orow[tid + 512] = f2bf(d2 * rs * w[tid + 512] + bvec[tid + 512]);
}

// fc1 partials (4, bf16 [2048][772]) + bias -> expanded overlapping slices
// Avqc[(r*4+q)][m] = h1[r][m+q]  (h1 never materialized)
__global__ __launch_bounds__(256) void reduce_fc1_expand(
        const short* __restrict__ part, const float* __restrict__ b,
        short* __restrict__ Avqc) {
    __shared__ float row[LD_H1];
    int r = blockIdx.x, tid = threadIdx.x;
    const size_t SP = (size_t)2048 * LD_H1;
    const short* pr = part + (size_t)r * LD_H1;
#pragma unroll
    for (int u = 0; u < 3; u++) {
        int c = tid + u * 256;
        float s = b[c];
#pragma unroll
        for (int z = 0; z < 4; z++) s += bf2f(pr[z * SP + c]);
        row[c] = s;
    }
    if (tid < 3) {
        int c = 768 + tid;
        float s = b[c];
#pragma unroll
        for (int z = 0; z < 4; z++) s += bf2f(pr[z * SP + c]);
        row[c] = s;
    }
    __syncthreads();
#pragma unroll
    for (int q = 0; q < 4; q++) {
        short* orow = Avqc + (size_t)(r * 4 + q) * 768;
#pragma unroll
        for (int u = 0; u < 3; u++) {
            int m = tid + u * 256;
            orow[m] = f2bf(row[m + q]);
        }
    }
}

// fc2 partials (8, bf16) + bias + residual x2 -> out fp32
__global__ __launch_bounds__(256) void reduce_fc2(
        const short* __restrict__ part, const float* __restrict__ b,
        const float* __restrict__ x2, float* __restrict__ out) {
    int t = blockIdx.x * 256 + threadIdx.x;     // 4-elem group; 393216 total
    int row = t / 192;
    int c = (t - row * 192) * 4;
    size_t off = (size_t)row * 768 + c;
    const size_t SP = (size_t)2048 * 768;
    float4 bb = *(const float4*)(b + c);
    float4 xx = *(const float4*)(x2 + off);
    float o0 = bb.x + xx.x, o1 = bb.y + xx.y, o2 = bb.z + xx.z, o3 = bb.w + xx.w;
#pragma unroll
    for (int z = 0; z < 8; z++) {
        short4 v = *(const short4*)(part + z * SP + off);
        o0 += bf2f(v.x); o1 += bf2f(v.y); o2 += bf2f(v.z); o3 += bf2f(v.w);
    }
    float4 o = make_float4(o0, o1, o2, o3);
    *(float4*)(out + off) = o;
}

// ---------------- MFMA fused attention (P-barrier removed) -----------------
// Pe/Pr are strictly per-wave LDS regions; wave-internal LDS ops execute in
// program order, so no __syncthreads is needed between P write and P read.

__global__ __launch_bounds__(256) void attn_mfma(
        const short* __restrict__ Qb,    // [2048][768] bf16
        const short* __restrict__ Kf,    // frag-major
        const short* __restrict__ Vf,    // frag-major
        const float* __restrict__ kn,    // [24][1024]
        const float* __restrict__ pond,
        short* __restrict__ vals) {      // [2048][768] bf16
    __shared__ __align__(16) short Kt[4096];
    __shared__ __align__(16) short Vt[4096];
    __shared__ float knl[1024];
    __shared__ float qn_l[4][16];
    __shared__ float is_l[4][16];
    __shared__ __align__(16) short Pe[4 * 16 * 72];
    __shared__ __align__(16) short Pr[4 * 16 * 72];

    const int tid = threadIdx.x;
    const int lane = tid & 63;
    const int wave = tid >> 6;
    const int ml = lane & 15;
    const int kq = lane >> 4;
    const int qt = blockIdx.x, h = blockIdx.y, b = blockIdx.z;
    const int bh = b * H_CNT + h;

    for (int i = tid; i < 1024; i += 256) knl[i] = kn[bh * 1024 + i];

    const int qrow = b * S_LEN + qt * 64 + wave * 16 + ml;
    const short* qp = Qb + (size_t)qrow * 768 + h * 64 + kq * 8;
    bf16x8 aq0 = *(const bf16x8*)qp;
    bf16x8 aq1 = *(const bf16x8*)(qp + 32);

    float qn_part = 0.f;
#pragma unroll
    for (int e = 0; e < 8; e++) {
        float v0 = bf2f(aq0[e]), v1 = bf2f(aq1[e]);
        qn_part += v0 * v0 + v1 * v1;
    }
    qn_part += __shfl_xor(qn_part, 16);
    qn_part += __shfl_xor(qn_part, 32);
    if (kq == 0) {
        qn_l[wave][ml] = qn_part;
        float sig = fminf(fmaxf(qn_part, 1e-8f), 1e4f);
        is_l[wave][ml] = 1.0f / sig;
    }
    __syncthreads();

    float qn_r[4], is_r[4];
#pragma unroll
    for (int r = 0; r < 4; r++) {
        qn_r[r] = qn_l[wave][kq * 4 + r];
        is_r[r] = is_l[wave][kq * 4 + r];
    }

    f32x4 Oe[4], Or[4];
#pragma unroll
    for (int dt = 0; dt < 4; dt++) { Oe[dt] = {0.f,0.f,0.f,0.f}; Or[dt] = {0.f,0.f,0.f,0.f}; }
    float es_p[4] = {0.f,0.f,0.f,0.f}, rs_p[4] = {0.f,0.f,0.f,0.f};

    const short* KfB = Kf + (size_t)bh * 65536;
    const short* VfB = Vf + (size_t)bh * 65536;
    short* PeW = Pe + wave * 1152;
    short* PrW = Pr + wave * 1152;

    for (int t = 0; t < 16; t++) {
        __syncthreads();   // all waves done reading prior Kt/Vt
        {
            const short* sk = KfB + t * 4096 + tid * 8;
            gld_lds16(Kt + tid * 8, sk);
            gld_lds16(Kt + 2048 + tid * 8, sk + 2048);
            const short* sv = VfB + t * 4096 + tid * 8;
            gld_lds16(Vt + tid * 8, sv);
            gld_lds16(Vt + 2048 + tid * 8, sv + 2048);
        }
        __syncthreads();   // tiles resident

#pragma unroll
        for (int jtl = 0; jtl < 4; jtl++) {
            bf16x8 bk0 = *(const bf16x8*)&Kt[(jtl * 2 + 0) * 512 + lane * 8];
            bf16x8 bk1 = *(const bf16x8*)&Kt[(jtl * 2 + 1) * 512 + lane * 8];
            f32x4 c = {0.f,0.f,0.f,0.f};
            c = __builtin_amdgcn_mfma_f32_16x16x32_bf16(aq0, bk0, c, 0, 0, 0);
            c = __builtin_amdgcn_mfma_f32_16x16x32_bf16(aq1, bk1, c, 0, 0, 0);
            float knj = knl[t * 64 + jtl * 16 + ml];
#pragma unroll
            for (int r = 0; r < 4; r++) {
                float qk = c[r];
                float e = __expf(qk * 0.125f);
                float tt = (2.f * qk - qn_r[r] - knj) * is_r[r];
                float rb = fminf(__expf(tt), 1.0f);
                es_p[r] += e; rs_p[r] += rb;
                PeW[(kq * 4 + r) * 72 + jtl * 16 + ml] = f2bf(e);
                PrW[(kq * 4 + r) * 72 + jtl * 16 + ml] = f2bf(rb);
            }
        }
        // (no barrier: P round-trip is wave-local)

#pragma unroll
        for (int jcl = 0; jcl < 2; jcl++) {
            bf16x8 pa_e = *(const bf16x8*)&PeW[ml * 72 + jcl * 32 + kq * 8];
            bf16x8 pa_r = *(const bf16x8*)&PrW[ml * 72 + jcl * 32 + kq * 8];
#pragma unroll
            for (int dt = 0; dt < 4; dt++) {
                bf16x8 bv = *(const bf16x8*)&Vt[(jcl * 4 + dt) * 512 + lane * 8];
                Oe[dt] = __builtin_amdgcn_mfma_f32_16x16x32_bf16(pa_e, bv, Oe[dt], 0, 0, 0);
                Or[dt] = __builtin_amdgcn_mfma_f32_16x16x32_bf16(pa_r, bv, Or[dt], 0, 0, 0);
            }
        }
    }

#pragma unroll
    for (int off = 1; off <= 8; off <<= 1) {
#pragma unroll
        for (int r = 0; r < 4; r++) {
            es_p[r] += __shfl_xor(es_p[r], off);
            rs_p[r] += __shfl_xor(rs_p[r], off);
        }
    }

    float p = pond[0];
    float sv = 1.0f / (1.0f + __expf(-p));
    float p0 = 1.0f - sv, p1 = sv;
    float blendinv = 1.0f / (p0 + p1 + 1e-7f);
    float we[4], wr[4];
#pragma unroll
    for (int r = 0; r < 4; r++) {
        we[r] = p0 * blendinv / es_p[r];
        wr[r] = p1 * blendinv / fmaxf(rs_p[r], 1e-8f);
    }

#pragma unroll
    for (int dt = 0; dt < 4; dt++) {
#pragma unroll
        for (int r = 0; r < 4; r++) {
            float v = Oe[dt][r] * we[r] + Or[dt][r] * wr[r];
            int token = b * S_LEN + qt * 64 + wave * 16 + kq * 4 + r;
            vals[(size_t)token * 768 + h * 64 + dt * 16 + ml] = f2bf(v);
        }
    }
}

// ---------------- launcher -------------------------------------------------

extern "C" void kernel_launch(void* const* d_in, const int* in_sizes, int n_in,
                              void* d_out, int out_size, void* d_ws, size_t ws_size,
                              hipStream_t stream) {
    const float* x     = (const float*)d_in[0];
    const float* ln1_w = (const float*)d_in[1];
    const float* ln1_b = (const float*)d_in[2];
    const float* Wq    = (const float*)d_in[3];
    const float* bq    = (const float*)d_in[4];
    const float* Wk    = (const float*)d_in[5];
    const float* bk    = (const float*)d_in[6];
    const float* Wv    = (const float*)d_in[7];
    const float* bv    = (const float*)d_in[8];
    const float* Wo    = (const float*)d_in[9];
    const float* bo    = (const float*)d_in[10];
    const float* pond  = (const float*)d_in[11];
    const float* ln2_w = (const float*)d_in[12];
    const float* ln2_b = (const float*)d_in[13];
    const float* fc1_W = (const float*)d_in[14];
    const float* fc1_b = (const float*)d_in[15];
    const float* vqc_W = (const float*)d_in[16];
    const float* vqc_b = (const float*)d_in[17];
    const float* fc2_W = (const float*)d_in[18];
    const float* fc2_b = (const float*)d_in[19];
    float* out = (float*)d_out;

    char* p = (char*)d_ws;
    short* Qb   = (short*)p;  p += (size_t)2048 * 768 * 2;
    short* Kfb  = (short*)p;  p += (size_t)2048 * 768 * 2;
    short* Vfb  = (short*)p;  p += (size_t)2048 * 768 * 2;
    float* x2   = (float*)p;  p += (size_t)2048 * 768 * 4;
    float* kn   = (float*)p;  p += (size_t)24576 * 4;
    float* bqkv = (float*)p;  p += 2304 * 4;
    short* actb = (short*)p;  p += (size_t)2048 * 768 * 2;
    short* g    = (short*)p;  p += (size_t)2048 * 3072 * 2;
    short* Avqc = (short*)p;  p += (size_t)8192 * 768 * 2;
    short* partb = (short*)p; p += (size_t)8 * 2048 * 768 * 2;   // split-K partials (25.2 MB)
    short* wreg = (short*)p;  p += (size_t)5900544 * 2;
    short* Wqkvb = wreg;
    short* Wob   = wreg + 1769472;
    short* fc1b  = wreg + 2359296;
    short* vqcb  = wreg + 2951424;
    short* fc2b  = wreg + 3541248;

    dim3 blk(256);

    // 0. weight conversion + fused bias concat
    convert_weights<<<5764, blk, 0, stream>>>(Wq, Wk, Wv, Wo, fc1_W, vqc_W, fc2_W, wreg,
                                              bq, bk, bv, bqkv);
    // 1. ln1 -> actb (bf16)
    ln_kernel<<<2048, blk, 0, stream>>>(x, ln1_w, ln1_b, actb);
    // 2. fused QKV projection (direct, 64-row tiles, 576 blocks = 2.25/CU)
    gemm_bf16<3, 64><<<dim3(18, 32, 1), blk, 0, stream>>>(actb, 768, Wqkvb, 768, bqkv,
                                                          Qb, 768, 0, Kfb, Vfb, 2304, 768, 0);
    // 3. k norms from Kf
    knorm2<<<96, blk, 0, stream>>>(Kfb, kn);
    // 4. MFMA attention -> vals (actb, bf16)
    attn_mfma<<<dim3(16, 12, 2), blk, 0, stream>>>(Qb, Kfb, Vfb, kn, pond, actb);
    // 5. Wo split-K x4, 64-row tiles (768 blocks = 3/CU exact)
    gemm_bf16<5, 64><<<dim3(6, 32, 4), blk, 0, stream>>>(actb, 768, Wob, 768, nullptr,
                                                         partb, 768, (size_t)2048 * 768,
                                                         nullptr, nullptr, 768, 192, 0);
    // 6. reduce + bo + residual(x) -> x2 fp32, fused ln2 -> actb
    reduce_wo_ln<<<2048, blk, 0, stream>>>(partb, bo, x, ln2_w, ln2_b, x2, actb);
    // 7. fc1 split-K x4 (N=771), 64-row tiles (896 blocks = 3.5/CU)
    gemm_bf16<5, 64><<<dim3(7, 32, 4), blk, 0, stream>>>(actb, 768, fc1b, 768, nullptr,
                                                         partb, LD_H1, (size_t)2048 * LD_H1,
                                                         nullptr, nullptr, N_FC1, 192, 0);
    // 8. reduce + bias + expand overlapping slices -> Avqc [8192][768]
    reduce_fc1_expand<<<2048, blk, 0, stream>>>(partb, fc1_b, Avqc);
    // 9. vqc (direct) + bias + gelu + transpose scatter, 64-row tiles
    //    (768 blocks = 3/CU exact)
    gemm_bf16<2, 64><<<dim3(6, 128, 1), blk, 0, stream>>>(Avqc, 768, vqcb, 768, vqc_b,
                                                          g, 3072, 0, nullptr, nullptr, 768, 768, 1);
    // 10. fc2 split-K x8, 128-row tiles (768 blocks = 3/CU exact)
    gemm_bf16<5, 128><<<dim3(6, 16, 8), blk, 0, stream>>>(g, 3072, fc2b, 3072, nullptr,
                                                          partb, 768, (size_t)2048 * 768,
                                                          nullptr, nullptr, 768, 384, 0);
    // 11. reduce + bias + residual(x2) -> out fp32
    reduce_fc2<<<1536, blk, 0, stream>>>(partb, fc2_b, x2, out);
}

// Round 11
// 259.406 us; speedup vs baseline: 1.1257x; 1.0068x over previous
//
#include <hip/hip_runtime.h>
#include <math.h>

#define E_DIM 768
#define S_LEN 1024
#define B_SZ 2
#define H_CNT 12
#define D_HEAD 64
#define M_DIM 768
#define Q_STRIDE 4
#define N_FC1 771            // only M+Q-1 columns of fc1 are consumed
#define LD_H1 772            // padded col count for fc1 partials

typedef __attribute__((ext_vector_type(8))) short bf16x8;
typedef __attribute__((ext_vector_type(4))) float f32x4;

#define AS1 __attribute__((address_space(1)))
#define AS3 __attribute__((address_space(3)))

__device__ __forceinline__ void gld_lds16(void* lds, const void* g) {
    __builtin_amdgcn_global_load_lds((const AS1 void*)g, (AS3 void*)lds, 16, 0, 0);
}

__device__ __forceinline__ short f2bf(float f) {
    unsigned u = __float_as_uint(f);
    unsigned r = (u + 0x7fffu + ((u >> 16) & 1u)) >> 16;
    return (short)r;
}

__device__ __forceinline__ float bf2f(short s) {
    return __uint_as_float(((unsigned)(unsigned short)s) << 16);
}

// ---------------- block reduction helper (256 threads, 4 waves) ------------

__device__ __forceinline__ float block_reduce_sum(float v, volatile float* red) {
#pragma unroll
    for (int off = 32; off > 0; off >>= 1) v += __shfl_xor(v, off);
    __syncthreads();
    if ((threadIdx.x & 63) == 0) red[threadIdx.x >> 6] = v;
    __syncthreads();
    return red[0] + red[1] + red[2] + red[3];
}

// ---------------- weight fp32 -> bf16 conversion (+ fused bias concat) -----

__global__ __launch_bounds__(256) void convert_weights(
        const float* __restrict__ Wq, const float* __restrict__ Wk,
        const float* __restrict__ Wv, const float* __restrict__ Wo,
        const float* __restrict__ fc1W, const float* __restrict__ vqcW,
        const float* __restrict__ fc2W, short* __restrict__ dst,
        const float* __restrict__ bq, const float* __restrict__ bk,
        const float* __restrict__ bv, float* __restrict__ bqkv) {
    if (blockIdx.x == 5763) {       // fused concat_bias
#pragma unroll
        for (int u = 0; u < 9; u++) {
            int i = threadIdx.x + u * 256;
            float v = (i < 768) ? bq[i] : (i < 1536) ? bk[i - 768] : bv[i - 1536];
            bqkv[i] = v;
        }
        return;
    }
    int t = blockIdx.x * 256 + threadIdx.x;       // float4 index
    if (t >= 1475136) return;                     // 5900544 / 4
    int e = t * 4;
    const float* src; int off;
    if      (e < 589824)  { src = Wq;   off = e; }
    else if (e < 1179648) { src = Wk;   off = e - 589824; }
    else if (e < 1769472) { src = Wv;   off = e - 1179648; }
    else if (e < 2359296) { src = Wo;   off = e - 1769472; }
    else if (e < 2951424) { src = fc1W; off = e - 2359296; }
    else if (e < 3541248) { src = vqcW; off = e - 2951424; }
    else                  { src = fc2W; off = e - 3541248; }
    float4 v = *(const float4*)(src + off);
    short4 o = make_short4(f2bf(v.x), f2bf(v.y), f2bf(v.z), f2bf(v.w));
    *(short4*)(dst + e) = o;
}

// ---------------- LayerNorm: one block per row, E=768, bf16 out ------------

__global__ __launch_bounds__(256) void ln_kernel(const float* __restrict__ x,
                                                 const float* __restrict__ w,
                                                 const float* __restrict__ b,
                                                 short* __restrict__ out) {
    __shared__ float red[4];
    int row = blockIdx.x;
    int tid = threadIdx.x;
    const float* xr = x + (size_t)row * E_DIM;
    float v0 = xr[tid], v1 = xr[tid + 256], v2 = xr[tid + 512];
    float s = block_reduce_sum(v0 + v1 + v2, red);
    float mu = s * (1.0f / E_DIM);
    float d0 = v0 - mu, d1 = v1 - mu, d2 = v2 - mu;
    float var = block_reduce_sum(d0 * d0 + d1 * d1 + d2 * d2, red) * (1.0f / E_DIM);
    float rs = rsqrtf(var + 1e-5f);
    short* orow = out + (size_t)row * E_DIM;
    orow[tid]       = f2bf(d0 * rs * w[tid]       + b[tid]);
    orow[tid + 256] = f2bf(d1 * rs * w[tid + 256] + b[tid + 256]);
    orow[tid + 512] = f2bf(d2 * rs * w[tid + 512] + b[tid + 512]);
}

// ---------------- k row norms from frag-major Kf ---------------------------

__global__ __launch_bounds__(256) void knorm2(const short* __restrict__ Kf,
                                              float* __restrict__ kn) {
    int idx = blockIdx.x * 256 + threadIdx.x;   // bh*1024 + s
    int s = idx & 1023, bh = idx >> 10;
    int jt = s >> 4, ml = s & 15;
    const short* base = Kf + (size_t)(bh * 64 + jt) * 1024 + ml * 8;
    float sum = 0.f;
#pragma unroll
    for (int c = 0; c < 2; c++)
#pragma unroll
        for (int kq = 0; kq < 4; kq++) {
            const short* p = base + c * 512 + kq * 128;
#pragma unroll
            for (int e = 0; e < 8; e++) { float v = bf2f(p[e]); sum += v * v; }
        }
    kn[idx] = sum;
}

// ---------------- bf16 MFMA NT GEMM (BK=64, double-buffered, MR-templated) -
// MR x 128 tile, BK=64 (two MRx32 sub-slabs). DOUBLE-BUFFERED: slab k+1 is
// prefetched right after the barrier, so its loads fly during the whole MFMA
// phase; one barrier per iteration. Safe now (R5 dbuf regression was the
// runtime-branch epilogue flipping the allocator into a 68-VGPR spill regime
// — R6-diagnosed; templated epilogue + launch_bounds(256,2) + MR=64's low
// acc pressure keep VGPR ~110). LDS 48 KB at MR=64 -> 3 blocks/CU, matching
// the 768-block balanced grids (R10 lesson).
// LDS k-slot XOR swizzle (slot = k ^ ((m>>1)&3)) -> 2-way bank alias (free).
// Split-K via blockIdx.z. OUTMODE:
//   2 = bias + GELU + bf16 transpose-scatter (vqc)
//   3 = QKV split: bias; Q row-major, K/V frag-major scatter
//   5 = bf16 partial (no bias) at outp + z*spitch

template <int OUTMODE, int MR>
__global__ __launch_bounds__(256, 2) void gemm_bf16(
        const short* __restrict__ A, int lda,
        const short* __restrict__ W, int ldw,
        const float* __restrict__ bias,
        void* __restrict__ outp, int ldo, size_t spitch,
        short* __restrict__ Kfp, short* __restrict__ Vfp,
        int N, int klen, int dogelu) {
    constexpr int MI = MR / 32;          // A-frag / acc row count per wave
    constexpr int AH = MR * 32;          // shorts per A half-slab
    constexpr int NA = MR / 64;          // A chunks per thread per half
    constexpr int ASL = 2 * AH;          // shorts per A slab (BK=64)
    __shared__ short At[2 * ASL];
    __shared__ short Bt[2 * 8192];
    const int tid = threadIdx.x;
    const int lane = tid & 63;
    const int wave = tid >> 6;
    const int wr = (wave >> 1) * (MI * 16);
    const int wc = (wave & 1) * 64;
    const int ml = lane & 15;
    const int kq = lane >> 4;
    const int row0 = blockIdx.y * MR;
    const int col0 = blockIdx.x * 128;
    const int kbase = blockIdx.z * klen;

    // staging: chunk c covers LDS shorts [c*8,c*8+8) = (m=c>>2, kslot=c&3);
    // source k-chunk = kslot ^ ((m>>1)&3)  (XOR swizzle)
    const short* Ag[NA]; int aoff[NA];
#pragma unroll
    for (int u = 0; u < NA; u++) {
        int c = tid + u * 256;
        int am = c >> 2, ak = ((c & 3) ^ ((am >> 1) & 3)) * 8;
        Ag[u] = A + (size_t)(row0 + am) * lda + ak + kbase;
        aoff[u] = c * 8;
    }
    const int c0 = tid, c1 = tid + 256;
    const int bm0 = c0 >> 2, bk0 = (((c0 & 3) ^ ((bm0 >> 1) & 3))) * 8;
    const int bm1 = c1 >> 2, bk1 = (((c1 & 3) ^ ((bm1 >> 1) & 3))) * 8;
    int wrow0 = col0 + bm0; if (wrow0 > N - 1) wrow0 = N - 1;
    int wrow1 = col0 + bm1; if (wrow1 > N - 1) wrow1 = N - 1;
    const short* Wg0 = W + (size_t)wrow0 * ldw + bk0 + kbase;
    const short* Wg1 = W + (size_t)wrow1 * ldw + bk1 + kbase;

    const int kxor = (kq ^ ((ml >> 1) & 3)) * 8;   // reader swizzle

    f32x4 acc[MI][4];
#pragma unroll
    for (int i = 0; i < MI; i++)
#pragma unroll
        for (int j = 0; j < 4; j++) acc[i][j] = {0.f, 0.f, 0.f, 0.f};

    auto stage = [&](int buf, int k0) {
        short* Ab = At + buf * ASL;
        short* Bb = Bt + buf * 8192;
#pragma unroll
        for (int u = 0; u < NA; u++) {
            gld_lds16(Ab + aoff[u], Ag[u] + k0);
            gld_lds16(Ab + AH + aoff[u], Ag[u] + k0 + 32);
        }
        gld_lds16(Bb + c0 * 8, Wg0 + k0);
        gld_lds16(Bb + c1 * 8, Wg1 + k0);
        gld_lds16(Bb + 4096 + c0 * 8, Wg0 + k0 + 32);
        gld_lds16(Bb + 4096 + c1 * 8, Wg1 + k0 + 32);
    };

    stage(0, 0);                 // prologue
    int cur = 0;
    for (int k0 = 0; k0 < klen; k0 += 64) {
        __syncthreads();         // slab cur resident; other buffer's readers done
        if (k0 + 64 < klen) stage(cur ^ 1, k0 + 64);   // in flight during MFMA
        const short* Ac = At + cur * ASL;
        const short* Bc = Bt + cur * 8192;
#pragma unroll
        for (int half = 0; half < 2; half++) {
            const short* Ah = Ac + half * AH;
            const short* Bh = Bc + half * 4096;
            bf16x8 af[MI], bfr[4];
#pragma unroll
            for (int i = 0; i < MI; i++)
                af[i] = *(const bf16x8*)&Ah[(wr + i * 16 + ml) * 32 + kxor];
#pragma unroll
            for (int j = 0; j < 4; j++)
                bfr[j] = *(const bf16x8*)&Bh[(wc + j * 16 + ml) * 32 + kxor];
#pragma unroll
            for (int i = 0; i < MI; i++)
#pragma unroll
                for (int j = 0; j < 4; j++)
                    acc[i][j] = __builtin_amdgcn_mfma_f32_16x16x32_bf16(af[i], bfr[j], acc[i][j], 0, 0, 0);
        }
        cur ^= 1;
    }

    // epilogue: C/D layout col = lane&15, row = (lane>>4)*4 + reg
#pragma unroll
    for (int i = 0; i < MI; i++) {
#pragma unroll
        for (int j = 0; j < 4; j++) {
#pragma unroll
            for (int rr = 0; rr < 4; rr++) {
                int r = row0 + wr + i * 16 + kq * 4 + rr;
                int c = col0 + wc + j * 16 + ml;
                if (c < N) {
                    float v = acc[i][j][rr];
                    if (OUTMODE < 4) v += bias[c];
                    if (OUTMODE == 2 && dogelu)
                        v = 0.5f * v * (1.0f + erff(v * 0.70710678118654752f));
                    if (OUTMODE == 2) {
                        ((short*)outp)[(size_t)(r >> 2) * ldo + c * 4 + (r & 3)] = f2bf(v);
                    } else if (OUTMODE == 5) {
                        ((short*)outp)[blockIdx.z * spitch + (size_t)r * ldo + c] = f2bf(v);
                    } else if (OUTMODE == 3) {
                        int s = r & 1023, bb = r >> 10;
                        if (c < 768) {
                            ((short*)outp)[(size_t)r * 768 + c] = f2bf(v);
                        } else if (c < 1536) {
                            int df = c - 768; int hh = df >> 6, d = df & 63;
                            int bh2 = bb * 12 + hh;
                            size_t idx = ((size_t)(bh2 * 64 + (s >> 4)) * 2 + (d >> 5)) * 512
                                       + (size_t)((d >> 3) & 3) * 128 + (size_t)(s & 15) * 8 + (d & 7);
                            Kfp[idx] = f2bf(v);
                        } else {
                            int df = c - 1536; int hh = df >> 6, d = df & 63;
                            int bh2 = bb * 12 + hh;
                            size_t idx = ((size_t)(bh2 * 32 + (s >> 5))) * 2048
                                       + (size_t)(d >> 4) * 512 + (size_t)((s >> 3) & 3) * 128
                                       + (size_t)(d & 15) * 8 + (s & 7);
                            Vfp[idx] = f2bf(v);
                        }
                    }
                }
            }
        }
    }
}

// ---------------- split-K reduce kernels -----------------------------------

// Wo partials (4, bf16) + bo + residual x -> x2 fp32, then LN(ln2) -> y bf16
__global__ __launch_bounds__(256) void reduce_wo_ln(
        const short* __restrict__ part, const float* __restrict__ bo,
        const float* __restrict__ x, const float* __restrict__ w,
        const float* __restrict__ bvec, float* __restrict__ x2,
        short* __restrict__ y) {
    __shared__ float red[4];
    int row = blockIdx.x, tid = threadIdx.x;
    const size_t SP = (size_t)2048 * 768;
    const short* pr = part + (size_t)row * 768;
    const float* xr = x + (size_t)row * 768;
    float* x2r = x2 + (size_t)row * 768;
    float v[3];
#pragma unroll
    for (int u = 0; u < 3; u++) {
        int c = tid + u * 256;
        float s = bo[c] + xr[c];
#pragma unroll
        for (int z = 0; z < 4; z++) s += bf2f(pr[z * SP + c]);
        v[u] = s; x2r[c] = s;
    }
    float s = block_reduce_sum(v[0] + v[1] + v[2], red);
    float mu = s * (1.0f / 768.f);
    float d0 = v[0] - mu, d1 = v[1] - mu, d2 = v[2] - mu;
    float var = block_reduce_sum(d0 * d0 + d1 * d1 + d2 * d2, red) * (1.0f / 768.f);
    float rs = rsqrtf(var + 1e-5f);
    short* orow = y + (size_t)row * 768;
    orow[tid]       = f2bf(d0 * rs * w[tid]       + bvec[tid]);
    orow[tid + 256] = f2bf(d1 * rs * w[tid + 256] + bvec[tid + 256]);
    orow[tid + 512] = f2bf(d2 * rs * w[tid + 512] + bvec[tid + 512]);
}

// fc1 partials (4, bf16 [2048][772]) + bias -> expanded overlapping slices
// Avqc[(r*4+q)][m] = h1[r][m+q]  (h1 never materialized)
__global__ __launch_bounds__(256) void reduce_fc1_expand(
        const short* __restrict__ part, const float* __restrict__ b,
        short* __restrict__ Avqc) {
    __shared__ float row[LD_H1];
    int r = blockIdx.x, tid = threadIdx.x;
    const size_t SP = (size_t)2048 * LD_H1;
    const short* pr = part + (size_t)r * LD_H1;
#pragma unroll
    for (int u = 0; u < 3; u++) {
        int c = tid + u * 256;
        float s = b[c];
#pragma unroll
        for (int z = 0; z < 4; z++) s += bf2f(pr[z * SP + c]);
        row[c] = s;
    }
    if (tid < 3) {
        int c = 768 + tid;
        float s = b[c];
#pragma unroll
        for (int z = 0; z < 4; z++) s += bf2f(pr[z * SP + c]);
        row[c] = s;
    }
    __syncthreads();
#pragma unroll
    for (int q = 0; q < 4; q++) {
        short* orow = Avqc + (size_t)(r * 4 + q) * 768;
#pragma unroll
        for (int u = 0; u < 3; u++) {
            int m = tid + u * 256;
            orow[m] = f2bf(row[m + q]);
        }
    }
}

// fc2 partials (4, bf16) + bias + residual x2 -> out fp32
__global__ __launch_bounds__(256) void reduce_fc2(
        const short* __restrict__ part, const float* __restrict__ b,
        const float* __restrict__ x2, float* __restrict__ out) {
    int t = blockIdx.x * 256 + threadIdx.x;     // 4-elem group; 393216 total
    int row = t / 192;
    int c = (t - row * 192) * 4;
    size_t off = (size_t)row * 768 + c;
    const size_t SP = (size_t)2048 * 768;
    float4 bb = *(const float4*)(b + c);
    float4 xx = *(const float4*)(x2 + off);
    float o0 = bb.x + xx.x, o1 = bb.y + xx.y, o2 = bb.z + xx.z, o3 = bb.w + xx.w;
#pragma unroll
    for (int z = 0; z < 4; z++) {
        short4 v = *(const short4*)(part + z * SP + off);
        o0 += bf2f(v.x); o1 += bf2f(v.y); o2 += bf2f(v.z); o3 += bf2f(v.w);
    }
    float4 o = make_float4(o0, o1, o2, o3);
    *(float4*)(out + off) = o;
}

// ---------------- MFMA fused attention, KV-split x2 ------------------------
// grid (16, 12, 4): z = (b<<1)|half; each block does 8 of 16 KV tiles and
// writes fp32 Oe/Or partials (partE/partR, [half][2048][768]) plus per-row
// es/rs partial sums. The no-max formulation makes the cross-half combine
// purely linear; attn_reduce normalizes. 768 blocks = 3/CU exact (R10).
// Pe/Pr are per-wave LDS -> no barrier between P write and P read.

__global__ __launch_bounds__(256) void attn_mfma(
        const short* __restrict__ Qb,    // [2048][768] bf16
        const short* __restrict__ Kf,    // frag-major
        const short* __restrict__ Vf,    // frag-major
        const float* __restrict__ kn,    // [24][1024]
        float* __restrict__ partO,       // [4][2048][768] fp32: E0,E1,R0,R1
        float* __restrict__ esb,         // [2][2][12][1024]
        float* __restrict__ rsb) {       // [2][2][12][1024]
    __shared__ __align__(16) short Kt[4096];
    __shared__ __align__(16) short Vt[4096];
    __shared__ float knl[1024];
    __shared__ float qn_l[4][16];
    __shared__ float is_l[4][16];
    __shared__ __align__(16) short Pe[4 * 16 * 72];
    __shared__ __align__(16) short Pr[4 * 16 * 72];

    const int tid = threadIdx.x;
    const int lane = tid & 63;
    const int wave = tid >> 6;
    const int ml = lane & 15;
    const int kq = lane >> 4;
    const int qt = blockIdx.x, h = blockIdx.y;
    const int b = blockIdx.z >> 1, half = blockIdx.z & 1;
    const int bh = b * H_CNT + h;

    for (int i = tid; i < 1024; i += 256) knl[i] = kn[bh * 1024 + i];

    const int qrow = b * S_LEN + qt * 64 + wave * 16 + ml;
    const short* qp = Qb + (size_t)qrow * 768 + h * 64 + kq * 8;
    bf16x8 aq0 = *(const bf16x8*)qp;
    bf16x8 aq1 = *(const bf16x8*)(qp + 32);

    float qn_part = 0.f;
#pragma unroll
    for (int e = 0; e < 8; e++) {
        float v0 = bf2f(aq0[e]), v1 = bf2f(aq1[e]);
        qn_part += v0 * v0 + v1 * v1;
    }
    qn_part += __shfl_xor(qn_part, 16);
    qn_part += __shfl_xor(qn_part, 32);
    if (kq == 0) {
        qn_l[wave][ml] = qn_part;
        float sig = fminf(fmaxf(qn_part, 1e-8f), 1e4f);
        is_l[wave][ml] = 1.0f / sig;
    }
    __syncthreads();

    float qn_r[4], is_r[4];
#pragma unroll
    for (int r = 0; r < 4; r++) {
        qn_r[r] = qn_l[wave][kq * 4 + r];
        is_r[r] = is_l[wave][kq * 4 + r];
    }

    f32x4 Oe[4], Or[4];
#pragma unroll
    for (int dt = 0; dt < 4; dt++) { Oe[dt] = {0.f,0.f,0.f,0.f}; Or[dt] = {0.f,0.f,0.f,0.f}; }
    float es_p[4] = {0.f,0.f,0.f,0.f}, rs_p[4] = {0.f,0.f,0.f,0.f};

    const short* KfB = Kf + (size_t)bh * 65536;
    const short* VfB = Vf + (size_t)bh * 65536;
    short* PeW = Pe + wave * 1152;
    short* PrW = Pr + wave * 1152;

    for (int t = half * 8; t < half * 8 + 8; t++) {
        __syncthreads();   // all waves done reading prior Kt/Vt
        {
            const short* sk = KfB + t * 4096 + tid * 8;
            gld_lds16(Kt + tid * 8, sk);
            gld_lds16(Kt + 2048 + tid * 8, sk + 2048);
            const short* sv = VfB + t * 4096 + tid * 8;
            gld_lds16(Vt + tid * 8, sv);
            gld_lds16(Vt + 2048 + tid * 8, sv + 2048);
        }
        __syncthreads();   // tiles resident

#pragma unroll
        for (int jtl = 0; jtl < 4; jtl++) {
            bf16x8 bk0 = *(const bf16x8*)&Kt[(jtl * 2 + 0) * 512 + lane * 8];
            bf16x8 bk1 = *(const bf16x8*)&Kt[(jtl * 2 + 1) * 512 + lane * 8];
            f32x4 c = {0.f,0.f,0.f,0.f};
            c = __builtin_amdgcn_mfma_f32_16x16x32_bf16(aq0, bk0, c, 0, 0, 0);
            c = __builtin_amdgcn_mfma_f32_16x16x32_bf16(aq1, bk1, c, 0, 0, 0);
            float knj = knl[t * 64 + jtl * 16 + ml];
#pragma unroll
            for (int r = 0; r < 4; r++) {
                float qk = c[r];
                float e = __expf(qk * 0.125f);
                float tt = (2.f * qk - qn_r[r] - knj) * is_r[r];
                float rb = fminf(__expf(tt), 1.0f);
                es_p[r] += e; rs_p[r] += rb;
                PeW[(kq * 4 + r) * 72 + jtl * 16 + ml] = f2bf(e);
                PrW[(kq * 4 + r) * 72 + jtl * 16 + ml] = f2bf(rb);
            }
        }
        // (no barrier: P round-trip is wave-local)

#pragma unroll
        for (int jcl = 0; jcl < 2; jcl++) {
            bf16x8 pa_e = *(const bf16x8*)&PeW[ml * 72 + jcl * 32 + kq * 8];
            bf16x8 pa_r = *(const bf16x8*)&PrW[ml * 72 + jcl * 32 + kq * 8];
#pragma unroll
            for (int dt = 0; dt < 4; dt++) {
                bf16x8 bv = *(const bf16x8*)&Vt[(jcl * 4 + dt) * 512 + lane * 8];
                Oe[dt] = __builtin_amdgcn_mfma_f32_16x16x32_bf16(pa_e, bv, Oe[dt], 0, 0, 0);
                Or[dt] = __builtin_amdgcn_mfma_f32_16x16x32_bf16(pa_r, bv, Or[dt], 0, 0, 0);
            }
        }
    }

#pragma unroll
    for (int off = 1; off <= 8; off <<= 1) {
#pragma unroll
        for (int r = 0; r < 4; r++) {
            es_p[r] += __shfl_xor(es_p[r], off);
            rs_p[r] += __shfl_xor(rs_p[r], off);
        }
    }
    if (ml == 0) {
        int base = ((half * 2 + b) * 12 + h) * 1024 + qt * 64 + wave * 16 + kq * 4;
#pragma unroll
        for (int r = 0; r < 4; r++) {
            esb[base + r] = es_p[r];
            rsb[base + r] = rs_p[r];
        }
    }

    const size_t SP = (size_t)2048 * 768;
    float* pe = partO + (size_t)half * SP;
    float* pr2 = partO + 2 * SP + (size_t)half * SP;
#pragma unroll
    for (int dt = 0; dt < 4; dt++) {
#pragma unroll
        for (int r = 0; r < 4; r++) {
            size_t idx = (size_t)(b * S_LEN + qt * 64 + wave * 16 + kq * 4 + r) * 768
                       + h * 64 + dt * 16 + ml;
            pe[idx] = Oe[dt][r];
            pr2[idx] = Or[dt][r];
        }
    }
}

// combine halves + normalize + blend -> vals bf16
__global__ __launch_bounds__(256) void attn_reduce(
        const float* __restrict__ partO, const float* __restrict__ esb,
        const float* __restrict__ rsb, const float* __restrict__ pond,
        short* __restrict__ vals) {
    int token = blockIdx.x, tid = threadIdx.x;
    int b = token >> 10, s = token & 1023;
    const size_t SP = (size_t)2048 * 768;
    float p = pond[0];
    float sv = 1.0f / (1.0f + __expf(-p));
    float p0 = 1.0f - sv, p1 = sv;
    float blendinv = 1.0f / (p0 + p1 + 1e-7f);
    size_t toff = (size_t)token * 768;
#pragma unroll
    for (int u = 0; u < 3; u++) {
        int c = tid + u * 256;
        int h = c >> 6;
        int eb = (b * 12 + h) * 1024 + s;
        float es = esb[eb] + esb[24576 + eb];
        float rs = rsb[eb] + rsb[24576 + eb];
        float we = p0 * blendinv / es;
        float wr = p1 * blendinv / fmaxf(rs, 1e-8f);
        float v = (partO[toff + c] + partO[SP + toff + c]) * we
                + (partO[2 * SP + toff + c] + partO[3 * SP + toff + c]) * wr;
        vals[toff + c] = f2bf(v);
    }
}

// ---------------- launcher -------------------------------------------------

extern "C" void kernel_launch(void* const* d_in, const int* in_sizes, int n_in,
                              void* d_out, int out_size, void* d_ws, size_t ws_size,
                              hipStream_t stream) {
    const float* x     = (const float*)d_in[0];
    const float* ln1_w = (const float*)d_in[1];
    const float* ln1_b = (const float*)d_in[2];
    const float* Wq    = (const float*)d_in[3];
    const float* bq    = (const float*)d_in[4];
    const float* Wk    = (const float*)d_in[5];
    const float* bk    = (const float*)d_in[6];
    const float* Wv    = (const float*)d_in[7];
    const float* bv    = (const float*)d_in[8];
    const float* Wo    = (const float*)d_in[9];
    const float* bo    = (const float*)d_in[10];
    const float* pond  = (const float*)d_in[11];
    const float* ln2_w = (const float*)d_in[12];
    const float* ln2_b = (const float*)d_in[13];
    const float* fc1_W = (const float*)d_in[14];
    const float* fc1_b = (const float*)d_in[15];
    const float* vqc_W = (const float*)d_in[16];
    const float* vqc_b = (const float*)d_in[17];
    const float* fc2_W = (const float*)d_in[18];
    const float* fc2_b = (const float*)d_in[19];
    float* out = (float*)d_out;

    char* p = (char*)d_ws;
    short* Qb   = (short*)p;  p += (size_t)2048 * 768 * 2;
    short* Kfb  = (short*)p;  p += (size_t)2048 * 768 * 2;
    short* Vfb  = (short*)p;  p += (size_t)2048 * 768 * 2;
    float* x2   = (float*)p;  p += (size_t)2048 * 768 * 4;
    float* kn   = (float*)p;  p += (size_t)24576 * 4;
    float* esb  = (float*)p;  p += (size_t)49152 * 4;
    float* rsb  = (float*)p;  p += (size_t)49152 * 4;
    float* bqkv = (float*)p;  p += 2304 * 4;
    short* actb = (short*)p;  p += (size_t)2048 * 768 * 2;
    short* g    = (short*)p;  p += (size_t)2048 * 3072 * 2;
    short* Avqc = (short*)p;  p += (size_t)8192 * 768 * 2;
    short* partb = (short*)p; p += (size_t)8 * 2048 * 768 * 2;   // 25.2 MB, aliased fp32 for attn
    short* wreg = (short*)p;  p += (size_t)5900544 * 2;
    short* Wqkvb = wreg;
    short* Wob   = wreg + 1769472;
    short* fc1b  = wreg + 2359296;
    short* vqcb  = wreg + 2951424;
    short* fc2b  = wreg + 3541248;
    float* partO = (float*)partb;    // [4][2048][768] fp32, attn partials

    dim3 blk(256);

    // 0. weight conversion + fused bias concat
    convert_weights<<<5764, blk, 0, stream>>>(Wq, Wk, Wv, Wo, fc1_W, vqc_W, fc2_W, wreg,
                                              bq, bk, bv, bqkv);
    // 1. ln1 -> actb (bf16)
    ln_kernel<<<2048, blk, 0, stream>>>(x, ln1_w, ln1_b, actb);
    // 2. fused QKV projection (direct, dbuf, 576 blocks)
    gemm_bf16<3, 64><<<dim3(18, 32, 1), blk, 0, stream>>>(actb, 768, Wqkvb, 768, bqkv,
                                                          Qb, 768, 0, Kfb, Vfb, 2304, 768, 0);
    // 3. k norms from Kf
    knorm2<<<96, blk, 0, stream>>>(Kfb, kn);
    // 4. MFMA attention, KV-split x2 (768 blocks = 3/CU) -> fp32 partials
    attn_mfma<<<dim3(16, 12, 4), blk, 0, stream>>>(Qb, Kfb, Vfb, kn, partO, esb, rsb);
    // 5. combine + normalize + blend -> vals (actb)
    attn_reduce<<<2048, blk, 0, stream>>>(partO, esb, rsb, pond, actb);
    // 6. Wo split-K x4 (768 blocks = 3/CU)
    gemm_bf16<5, 64><<<dim3(6, 32, 4), blk, 0, stream>>>(actb, 768, Wob, 768, nullptr,
                                                         partb, 768, (size_t)2048 * 768,
                                                         nullptr, nullptr, 768, 192, 0);
    // 7. reduce + bo + residual(x) -> x2 fp32, fused ln2 -> actb
    reduce_wo_ln<<<2048, blk, 0, stream>>>(partb, bo, x, ln2_w, ln2_b, x2, actb);
    // 8. fc1 split-K x4 (N=771, 896 blocks)
    gemm_bf16<5, 64><<<dim3(7, 32, 4), blk, 0, stream>>>(actb, 768, fc1b, 768, nullptr,
                                                         partb, LD_H1, (size_t)2048 * LD_H1,
                                                         nullptr, nullptr, N_FC1, 192, 0);
    // 9. reduce + bias + expand overlapping slices -> Avqc [8192][768]
    reduce_fc1_expand<<<2048, blk, 0, stream>>>(partb, fc1_b, Avqc);
    // 10. vqc (direct) + bias + gelu + transpose scatter (768 blocks = 3/CU)
    gemm_bf16<2, 64><<<dim3(6, 128, 1), blk, 0, stream>>>(Avqc, 768, vqcb, 768, vqc_b,
                                                          g, 3072, 0, nullptr, nullptr, 768, 768, 1);
    // 11. fc2 split-K x4 (768 blocks = 3/CU)
    gemm_bf16<5, 64><<<dim3(6, 32, 4), blk, 0, stream>>>(g, 3072, fc2b, 3072, nullptr,
                                                         partb, 768, (size_t)2048 * 768,
                                                         nullptr, nullptr, 768, 768, 0);
    // 12. reduce + bias + residual(x2) -> out fp32
    reduce_fc2<<<1536, blk, 0, stream>>>(partb, fc2_b, x2, out);
}

// Round 12
// 257.815 us; speedup vs baseline: 1.1327x; 1.0062x over previous
//
#include <hip/hip_runtime.h>
#include <math.h>

#define E_DIM 768
#define S_LEN 1024
#define B_SZ 2
#define H_CNT 12
#define D_HEAD 64
#define M_DIM 768
#define Q_STRIDE 4
#define N_FC1 771            // only M+Q-1 columns of fc1 are consumed

typedef __attribute__((ext_vector_type(8))) short bf16x8;
typedef __attribute__((ext_vector_type(4))) float f32x4;

#define AS1 __attribute__((address_space(1)))
#define AS3 __attribute__((address_space(3)))

__device__ __forceinline__ void gld_lds16(void* lds, const void* g) {
    __builtin_amdgcn_global_load_lds((const AS1 void*)g, (AS3 void*)lds, 16, 0, 0);
}

__device__ __forceinline__ short f2bf(float f) {
    unsigned u = __float_as_uint(f);
    unsigned r = (u + 0x7fffu + ((u >> 16) & 1u)) >> 16;
    return (short)r;
}

__device__ __forceinline__ float bf2f(short s) {
    return __uint_as_float(((unsigned)(unsigned short)s) << 16);
}

// ---------------- block reduction helper (256 threads, 4 waves) ------------

__device__ __forceinline__ float block_reduce_sum(float v, volatile float* red) {
#pragma unroll
    for (int off = 32; off > 0; off >>= 1) v += __shfl_xor(v, off);
    __syncthreads();
    if ((threadIdx.x & 63) == 0) red[threadIdx.x >> 6] = v;
    __syncthreads();
    return red[0] + red[1] + red[2] + red[3];
}

// ------------- preamble: ln1 + bias concat + weight conversion, one grid ---
// blocks 0..2047: ln1 rows -> actb; block 2048: bias concat; rest: weights.

__global__ __launch_bounds__(256) void preamble(
        const float* __restrict__ Wq, const float* __restrict__ Wk,
        const float* __restrict__ Wv, const float* __restrict__ Wo,
        const float* __restrict__ fc1W, const float* __restrict__ vqcW,
        const float* __restrict__ fc2W, short* __restrict__ dst,
        const float* __restrict__ bq, const float* __restrict__ bk,
        const float* __restrict__ bv, float* __restrict__ bqkv,
        const float* __restrict__ x, const float* __restrict__ ln1_w,
        const float* __restrict__ ln1_b, short* __restrict__ actb) {
    __shared__ float red[4];
    int tid = threadIdx.x;
    if (blockIdx.x < 2048) {          // ln1
        int row = blockIdx.x;
        const float* xr = x + (size_t)row * E_DIM;
        float v0 = xr[tid], v1 = xr[tid + 256], v2 = xr[tid + 512];
        float s = block_reduce_sum(v0 + v1 + v2, red);
        float mu = s * (1.0f / E_DIM);
        float d0 = v0 - mu, d1 = v1 - mu, d2 = v2 - mu;
        float var = block_reduce_sum(d0 * d0 + d1 * d1 + d2 * d2, red) * (1.0f / E_DIM);
        float rs = rsqrtf(var + 1e-5f);
        short* orow = actb + (size_t)row * E_DIM;
        orow[tid]       = f2bf(d0 * rs * ln1_w[tid]       + ln1_b[tid]);
        orow[tid + 256] = f2bf(d1 * rs * ln1_w[tid + 256] + ln1_b[tid + 256]);
        orow[tid + 512] = f2bf(d2 * rs * ln1_w[tid + 512] + ln1_b[tid + 512]);
        return;
    }
    if (blockIdx.x == 2048) {         // bias concat
#pragma unroll
        for (int u = 0; u < 9; u++) {
            int i = tid + u * 256;
            float v = (i < 768) ? bq[i] : (i < 1536) ? bk[i - 768] : bv[i - 1536];
            bqkv[i] = v;
        }
        return;
    }
    int t = (blockIdx.x - 2049) * 256 + tid;      // float4 index
    if (t >= 1475136) return;                     // 5900544 / 4
    int e = t * 4;
    const float* src; int off;
    if      (e < 589824)  { src = Wq;   off = e; }
    else if (e < 1179648) { src = Wk;   off = e - 589824; }
    else if (e < 1769472) { src = Wv;   off = e - 1179648; }
    else if (e < 2359296) { src = Wo;   off = e - 1769472; }
    else if (e < 2951424) { src = fc1W; off = e - 2359296; }
    else if (e < 3541248) { src = vqcW; off = e - 2951424; }
    else                  { src = fc2W; off = e - 3541248; }
    float4 v = *(const float4*)(src + off);
    short4 o = make_short4(f2bf(v.x), f2bf(v.y), f2bf(v.z), f2bf(v.w));
    *(short4*)(dst + e) = o;
}

// ---------------- bf16 MFMA NT GEMM (BK=64, double-buffered, MR-templated) -
// MR x 128 tile, BK=64 (two MRx32 sub-slabs), double-buffered (one barrier
// per iteration; prefetch flies during MFMA phase). LDS 48 KB at MR=64 ->
// 3 blocks/CU, matching the 768-block balanced grids (R10).
// R5/R6 lesson: runtime-branch epilogues flip the allocator into a 68-VGPR
// accumulator-spill regime; keep OUTMODE a template + launch_bounds(256,2).
// LDS k-slot XOR swizzle (slot = k ^ ((m>>1)&3)) -> 2-way bank alias (free).
// OUTMODE: 2 = bias+GELU+bf16 transpose-scatter (vqc); 3 = QKV split;
//          5 = bf16 partial (no bias) at outp + z*spitch.

template <int OUTMODE, int MR>
__global__ __launch_bounds__(256, 2) void gemm_bf16(
        const short* __restrict__ A, int lda,
        const short* __restrict__ W, int ldw,
        const float* __restrict__ bias,
        void* __restrict__ outp, int ldo, size_t spitch,
        short* __restrict__ Kfp, short* __restrict__ Vfp,
        int N, int klen, int dogelu) {
    constexpr int MI = MR / 32;
    constexpr int AH = MR * 32;
    constexpr int NA = MR / 64;
    constexpr int ASL = 2 * AH;
    __shared__ short At[2 * ASL];
    __shared__ short Bt[2 * 8192];
    const int tid = threadIdx.x;
    const int lane = tid & 63;
    const int wave = tid >> 6;
    const int wr = (wave >> 1) * (MI * 16);
    const int wc = (wave & 1) * 64;
    const int ml = lane & 15;
    const int kq = lane >> 4;
    const int row0 = blockIdx.y * MR;
    const int col0 = blockIdx.x * 128;
    const int kbase = blockIdx.z * klen;

    const short* Ag[NA]; int aoff[NA];
#pragma unroll
    for (int u = 0; u < NA; u++) {
        int c = tid + u * 256;
        int am = c >> 2, ak = ((c & 3) ^ ((am >> 1) & 3)) * 8;
        Ag[u] = A + (size_t)(row0 + am) * lda + ak + kbase;
        aoff[u] = c * 8;
    }
    const int c0 = tid, c1 = tid + 256;
    const int bm0 = c0 >> 2, bk0 = (((c0 & 3) ^ ((bm0 >> 1) & 3))) * 8;
    const int bm1 = c1 >> 2, bk1 = (((c1 & 3) ^ ((bm1 >> 1) & 3))) * 8;
    int wrow0 = col0 + bm0; if (wrow0 > N - 1) wrow0 = N - 1;
    int wrow1 = col0 + bm1; if (wrow1 > N - 1) wrow1 = N - 1;
    const short* Wg0 = W + (size_t)wrow0 * ldw + bk0 + kbase;
    const short* Wg1 = W + (size_t)wrow1 * ldw + bk1 + kbase;

    const int kxor = (kq ^ ((ml >> 1) & 3)) * 8;

    f32x4 acc[MI][4];
#pragma unroll
    for (int i = 0; i < MI; i++)
#pragma unroll
        for (int j = 0; j < 4; j++) acc[i][j] = {0.f, 0.f, 0.f, 0.f};

    auto stage = [&](int buf, int k0) {
        short* Ab = At + buf * ASL;
        short* Bb = Bt + buf * 8192;
#pragma unroll
        for (int u = 0; u < NA; u++) {
            gld_lds16(Ab + aoff[u], Ag[u] + k0);
            gld_lds16(Ab + AH + aoff[u], Ag[u] + k0 + 32);
        }
        gld_lds16(Bb + c0 * 8, Wg0 + k0);
        gld_lds16(Bb + c1 * 8, Wg1 + k0);
        gld_lds16(Bb + 4096 + c0 * 8, Wg0 + k0 + 32);
        gld_lds16(Bb + 4096 + c1 * 8, Wg1 + k0 + 32);
    };

    stage(0, 0);
    int cur = 0;
    for (int k0 = 0; k0 < klen; k0 += 64) {
        __syncthreads();
        if (k0 + 64 < klen) stage(cur ^ 1, k0 + 64);
        const short* Ac = At + cur * ASL;
        const short* Bc = Bt + cur * 8192;
#pragma unroll
        for (int half = 0; half < 2; half++) {
            const short* Ah = Ac + half * AH;
            const short* Bh = Bc + half * 4096;
            bf16x8 af[MI], bfr[4];
#pragma unroll
            for (int i = 0; i < MI; i++)
                af[i] = *(const bf16x8*)&Ah[(wr + i * 16 + ml) * 32 + kxor];
#pragma unroll
            for (int j = 0; j < 4; j++)
                bfr[j] = *(const bf16x8*)&Bh[(wc + j * 16 + ml) * 32 + kxor];
#pragma unroll
            for (int i = 0; i < MI; i++)
#pragma unroll
                for (int j = 0; j < 4; j++)
                    acc[i][j] = __builtin_amdgcn_mfma_f32_16x16x32_bf16(af[i], bfr[j], acc[i][j], 0, 0, 0);
        }
        cur ^= 1;
    }

    // epilogue: C/D layout col = lane&15, row = (lane>>4)*4 + reg
#pragma unroll
    for (int i = 0; i < MI; i++) {
#pragma unroll
        for (int j = 0; j < 4; j++) {
#pragma unroll
            for (int rr = 0; rr < 4; rr++) {
                int r = row0 + wr + i * 16 + kq * 4 + rr;
                int c = col0 + wc + j * 16 + ml;
                if (c < N) {
                    float v = acc[i][j][rr];
                    if (OUTMODE < 4) v += bias[c];
                    if (OUTMODE == 2 && dogelu)
                        v = 0.5f * v * (1.0f + erff(v * 0.70710678118654752f));
                    if (OUTMODE == 2) {
                        ((short*)outp)[(size_t)(r >> 2) * ldo + c * 4 + (r & 3)] = f2bf(v);
                    } else if (OUTMODE == 5) {
                        ((short*)outp)[blockIdx.z * spitch + (size_t)r * ldo + c] = f2bf(v);
                    } else if (OUTMODE == 3) {
                        int s = r & 1023, bb = r >> 10;
                        if (c < 768) {
                            ((short*)outp)[(size_t)r * 768 + c] = f2bf(v);
                        } else if (c < 1536) {
                            int df = c - 768; int hh = df >> 6, d = df & 63;
                            int bh2 = bb * 12 + hh;
                            size_t idx = ((size_t)(bh2 * 64 + (s >> 4)) * 2 + (d >> 5)) * 512
                                       + (size_t)((d >> 3) & 3) * 128 + (size_t)(s & 15) * 8 + (d & 7);
                            Kfp[idx] = f2bf(v);
                        } else {
                            int df = c - 1536; int hh = df >> 6, d = df & 63;
                            int bh2 = bb * 12 + hh;
                            size_t idx = ((size_t)(bh2 * 32 + (s >> 5))) * 2048
                                       + (size_t)(d >> 4) * 512 + (size_t)((s >> 3) & 3) * 128
                                       + (size_t)(d & 15) * 8 + (s & 7);
                            Vfp[idx] = f2bf(v);
                        }
                    }
                }
            }
        }
    }
}

// ---------------- split-K reduce kernels -----------------------------------

// Wo partials (4, bf16) + bo + residual x -> x2 fp32, then LN(ln2) -> y bf16
__global__ __launch_bounds__(256) void reduce_wo_ln(
        const short* __restrict__ part, const float* __restrict__ bo,
        const float* __restrict__ x, const float* __restrict__ w,
        const float* __restrict__ bvec, float* __restrict__ x2,
        short* __restrict__ y) {
    __shared__ float red[4];
    int row = blockIdx.x, tid = threadIdx.x;
    const size_t SP = (size_t)2048 * 768;
    const short* pr = part + (size_t)row * 768;
    const float* xr = x + (size_t)row * 768;
    float* x2r = x2 + (size_t)row * 768;
    float v[3];
#pragma unroll
    for (int u = 0; u < 3; u++) {
        int c = tid + u * 256;
        float s = bo[c] + xr[c];
#pragma unroll
        for (int z = 0; z < 4; z++) s += bf2f(pr[z * SP + c]);
        v[u] = s; x2r[c] = s;
    }
    float s = block_reduce_sum(v[0] + v[1] + v[2], red);
    float mu = s * (1.0f / 768.f);
    float d0 = v[0] - mu, d1 = v[1] - mu, d2 = v[2] - mu;
    float var = block_reduce_sum(d0 * d0 + d1 * d1 + d2 * d2, red) * (1.0f / 768.f);
    float rs = rsqrtf(var + 1e-5f);
    short* orow = y + (size_t)row * 768;
    orow[tid]       = f2bf(d0 * rs * w[tid]       + bvec[tid]);
    orow[tid + 256] = f2bf(d1 * rs * w[tid + 256] + bvec[tid + 256]);
    orow[tid + 512] = f2bf(d2 * rs * w[tid + 512] + bvec[tid + 512]);
}

// fc1 partials (4, bf16 [2048][768], cols 0..767) + bias -> expanded slices.
// Cols 768..770 (the 3 extra overlapping-slice columns) are computed here as
// block-reduced dots y[r].fc1_W[768+k] — lets the fc1 GEMM run an exact
// 768-block grid (R10 balance lesson). Avqc[(r*4+q)][m] = h1[r][m+q].
__global__ __launch_bounds__(256) void reduce_fc1_expand(
        const short* __restrict__ part, const float* __restrict__ b,
        const short* __restrict__ y, const short* __restrict__ w768,
        short* __restrict__ Avqc) {
    __shared__ float row[772];
    __shared__ float red[4];
    int r = blockIdx.x, tid = threadIdx.x;
    const size_t SP = (size_t)2048 * 768;
    const short* pr = part + (size_t)r * 768;
#pragma unroll
    for (int u = 0; u < 3; u++) {
        int c = tid + u * 256;
        float s = b[c];
#pragma unroll
        for (int z = 0; z < 4; z++) s += bf2f(pr[z * SP + c]);
        row[c] = s;
    }
    const short* yr = y + (size_t)r * 768;
    float y0 = bf2f(yr[tid]), y1 = bf2f(yr[tid + 256]), y2 = bf2f(yr[tid + 512]);
#pragma unroll
    for (int k = 0; k < 3; k++) {
        const short* wk = w768 + k * 768;
        float s = y0 * bf2f(wk[tid]) + y1 * bf2f(wk[tid + 256]) + y2 * bf2f(wk[tid + 512]);
        s = block_reduce_sum(s, red);
        if (tid == 0) row[768 + k] = s + b[768 + k];
    }
    __syncthreads();
#pragma unroll
    for (int q = 0; q < 4; q++) {
        short* orow = Avqc + (size_t)(r * 4 + q) * 768;
#pragma unroll
        for (int u = 0; u < 3; u++) {
            int m = tid + u * 256;
            orow[m] = f2bf(row[m + q]);
        }
    }
}

// fc2 partials (4, bf16) + bias + residual x2 -> out fp32
__global__ __launch_bounds__(256) void reduce_fc2(
        const short* __restrict__ part, const float* __restrict__ b,
        const float* __restrict__ x2, float* __restrict__ out) {
    int t = blockIdx.x * 256 + threadIdx.x;
    int row = t / 192;
    int c = (t - row * 192) * 4;
    size_t off = (size_t)row * 768 + c;
    const size_t SP = (size_t)2048 * 768;
    float4 bb = *(const float4*)(b + c);
    float4 xx = *(const float4*)(x2 + off);
    float o0 = bb.x + xx.x, o1 = bb.y + xx.y, o2 = bb.z + xx.z, o3 = bb.w + xx.w;
#pragma unroll
    for (int z = 0; z < 4; z++) {
        short4 v = *(const short4*)(part + z * SP + off);
        o0 += bf2f(v.x); o1 += bf2f(v.y); o2 += bf2f(v.z); o3 += bf2f(v.w);
    }
    float4 o = make_float4(o0, o1, o2, o3);
    *(float4*)(out + off) = o;
}

// ---------------- MFMA fused attention, KV-split x2 ------------------------
// grid (16, 12, 4): z = (b<<1)|half; 8 KV tiles per block; bf16 Oe/Or
// partials (normalized later, so 0.4% rel err is free) + fp32 es/rs sums.
// k-norms computed INLINE from the already-loaded B-frags (bk0/bk1): lanes
// {ml,ml+16,ml+32,ml+48} hold all 64 d of j=jtl*16+ml -> 2 shuffles.
// Pe/Pr are per-wave LDS -> no barrier between P write and read.

__global__ __launch_bounds__(256) void attn_mfma(
        const short* __restrict__ Qb,    // [2048][768] bf16
        const short* __restrict__ Kf,    // frag-major
        const short* __restrict__ Vf,    // frag-major
        short* __restrict__ partO,       // [4][2048][768] bf16: E0,E1,R0,R1
        float* __restrict__ esb,         // [2][2][12][1024]
        float* __restrict__ rsb) {
    __shared__ __align__(16) short Kt[4096];
    __shared__ __align__(16) short Vt[4096];
    __shared__ float qn_l[4][16];
    __shared__ float is_l[4][16];
    __shared__ __align__(16) short Pe[4 * 16 * 72];
    __shared__ __align__(16) short Pr[4 * 16 * 72];

    const int tid = threadIdx.x;
    const int lane = tid & 63;
    const int wave = tid >> 6;
    const int ml = lane & 15;
    const int kq = lane >> 4;
    const int qt = blockIdx.x, h = blockIdx.y;
    const int b = blockIdx.z >> 1, half = blockIdx.z & 1;
    const int bh = b * H_CNT + h;

    const int qrow = b * S_LEN + qt * 64 + wave * 16 + ml;
    const short* qp = Qb + (size_t)qrow * 768 + h * 64 + kq * 8;
    bf16x8 aq0 = *(const bf16x8*)qp;
    bf16x8 aq1 = *(const bf16x8*)(qp + 32);

    float qn_part = 0.f;
#pragma unroll
    for (int e = 0; e < 8; e++) {
        float v0 = bf2f(aq0[e]), v1 = bf2f(aq1[e]);
        qn_part += v0 * v0 + v1 * v1;
    }
    qn_part += __shfl_xor(qn_part, 16);
    qn_part += __shfl_xor(qn_part, 32);
    if (kq == 0) {
        qn_l[wave][ml] = qn_part;
        float sig = fminf(fmaxf(qn_part, 1e-8f), 1e4f);
        is_l[wave][ml] = 1.0f / sig;
    }
    __syncthreads();

    float qn_r[4], is_r[4];
#pragma unroll
    for (int r = 0; r < 4; r++) {
        qn_r[r] = qn_l[wave][kq * 4 + r];
        is_r[r] = is_l[wave][kq * 4 + r];
    }

    f32x4 Oe[4], Or[4];
#pragma unroll
    for (int dt = 0; dt < 4; dt++) { Oe[dt] = {0.f,0.f,0.f,0.f}; Or[dt] = {0.f,0.f,0.f,0.f}; }
    float es_p[4] = {0.f,0.f,0.f,0.f}, rs_p[4] = {0.f,0.f,0.f,0.f};

    const short* KfB = Kf + (size_t)bh * 65536;
    const short* VfB = Vf + (size_t)bh * 65536;
    short* PeW = Pe + wave * 1152;
    short* PrW = Pr + wave * 1152;

    for (int t = half * 8; t < half * 8 + 8; t++) {
        __syncthreads();
        {
            const short* sk = KfB + t * 4096 + tid * 8;
            gld_lds16(Kt + tid * 8, sk);
            gld_lds16(Kt + 2048 + tid * 8, sk + 2048);
            const short* sv = VfB + t * 4096 + tid * 8;
            gld_lds16(Vt + tid * 8, sv);
            gld_lds16(Vt + 2048 + tid * 8, sv + 2048);
        }
        __syncthreads();

#pragma unroll
        for (int jtl = 0; jtl < 4; jtl++) {
            bf16x8 bk0 = *(const bf16x8*)&Kt[(jtl * 2 + 0) * 512 + lane * 8];
            bf16x8 bk1 = *(const bf16x8*)&Kt[(jtl * 2 + 1) * 512 + lane * 8];
            // inline k-norm for j = jtl*16 + ml
            float knp = 0.f;
#pragma unroll
            for (int e = 0; e < 8; e++) {
                float k0v = bf2f(bk0[e]), k1v = bf2f(bk1[e]);
                knp += k0v * k0v + k1v * k1v;
            }
            knp += __shfl_xor(knp, 16);
            knp += __shfl_xor(knp, 32);
            f32x4 c = {0.f,0.f,0.f,0.f};
            c = __builtin_amdgcn_mfma_f32_16x16x32_bf16(aq0, bk0, c, 0, 0, 0);
            c = __builtin_amdgcn_mfma_f32_16x16x32_bf16(aq1, bk1, c, 0, 0, 0);
#pragma unroll
            for (int r = 0; r < 4; r++) {
                float qk = c[r];
                float e = __expf(qk * 0.125f);
                float tt = (2.f * qk - qn_r[r] - knp) * is_r[r];
                float rb = fminf(__expf(tt), 1.0f);
                es_p[r] += e; rs_p[r] += rb;
                PeW[(kq * 4 + r) * 72 + jtl * 16 + ml] = f2bf(e);
                PrW[(kq * 4 + r) * 72 + jtl * 16 + ml] = f2bf(rb);
            }
        }
        // (no barrier: P round-trip is wave-local)

#pragma unroll
        for (int jcl = 0; jcl < 2; jcl++) {
            bf16x8 pa_e = *(const bf16x8*)&PeW[ml * 72 + jcl * 32 + kq * 8];
            bf16x8 pa_r = *(const bf16x8*)&PrW[ml * 72 + jcl * 32 + kq * 8];
#pragma unroll
            for (int dt = 0; dt < 4; dt++) {
                bf16x8 bv = *(const bf16x8*)&Vt[(jcl * 4 + dt) * 512 + lane * 8];
                Oe[dt] = __builtin_amdgcn_mfma_f32_16x16x32_bf16(pa_e, bv, Oe[dt], 0, 0, 0);
                Or[dt] = __builtin_amdgcn_mfma_f32_16x16x32_bf16(pa_r, bv, Or[dt], 0, 0, 0);
            }
        }
    }

#pragma unroll
    for (int off = 1; off <= 8; off <<= 1) {
#pragma unroll
        for (int r = 0; r < 4; r++) {
            es_p[r] += __shfl_xor(es_p[r], off);
            rs_p[r] += __shfl_xor(rs_p[r], off);
        }
    }
    if (ml == 0) {
        int base = ((half * 2 + b) * 12 + h) * 1024 + qt * 64 + wave * 16 + kq * 4;
#pragma unroll
        for (int r = 0; r < 4; r++) {
            esb[base + r] = es_p[r];
            rsb[base + r] = rs_p[r];
        }
    }

    const size_t SP = (size_t)2048 * 768;
    short* pe = partO + (size_t)half * SP;
    short* pr2 = partO + 2 * SP + (size_t)half * SP;
#pragma unroll
    for (int dt = 0; dt < 4; dt++) {
#pragma unroll
        for (int r = 0; r < 4; r++) {
            size_t idx = (size_t)(b * S_LEN + qt * 64 + wave * 16 + kq * 4 + r) * 768
                       + h * 64 + dt * 16 + ml;
            pe[idx] = f2bf(Oe[dt][r]);
            pr2[idx] = f2bf(Or[dt][r]);
        }
    }
}

// combine halves + normalize + blend -> vals bf16
__global__ __launch_bounds__(256) void attn_reduce(
        const short* __restrict__ partO, const float* __restrict__ esb,
        const float* __restrict__ rsb, const float* __restrict__ pond,
        short* __restrict__ vals) {
    int token = blockIdx.x, tid = threadIdx.x;
    int b = token >> 10, s = token & 1023;
    const size_t SP = (size_t)2048 * 768;
    float p = pond[0];
    float sv = 1.0f / (1.0f + __expf(-p));
    float p0 = 1.0f - sv, p1 = sv;
    float blendinv = 1.0f / (p0 + p1 + 1e-7f);
    size_t toff = (size_t)token * 768;
#pragma unroll
    for (int u = 0; u < 3; u++) {
        int c = tid + u * 256;
        int h = c >> 6;
        int eb = (b * 12 + h) * 1024 + s;
        float es = esb[eb] + esb[24576 + eb];
        float rs = rsb[eb] + rsb[24576 + eb];
        float we = p0 * blendinv / es;
        float wr = p1 * blendinv / fmaxf(rs, 1e-8f);
        float v = (bf2f(partO[toff + c]) + bf2f(partO[SP + toff + c])) * we
                + (bf2f(partO[2 * SP + toff + c]) + bf2f(partO[3 * SP + toff + c])) * wr;
        vals[toff + c] = f2bf(v);
    }
}

// ---------------- launcher -------------------------------------------------

extern "C" void kernel_launch(void* const* d_in, const int* in_sizes, int n_in,
                              void* d_out, int out_size, void* d_ws, size_t ws_size,
                              hipStream_t stream) {
    const float* x     = (const float*)d_in[0];
    const float* ln1_w = (const float*)d_in[1];
    const float* ln1_b = (const float*)d_in[2];
    const float* Wq    = (const float*)d_in[3];
    const float* bq    = (const float*)d_in[4];
    const float* Wk    = (const float*)d_in[5];
    const float* bk    = (const float*)d_in[6];
    const float* Wv    = (const float*)d_in[7];
    const float* bv    = (const float*)d_in[8];
    const float* Wo    = (const float*)d_in[9];
    const float* bo    = (const float*)d_in[10];
    const float* pond  = (const float*)d_in[11];
    const float* ln2_w = (const float*)d_in[12];
    const float* ln2_b = (const float*)d_in[13];
    const float* fc1_W = (const float*)d_in[14];
    const float* fc1_b = (const float*)d_in[15];
    const float* vqc_W = (const float*)d_in[16];
    const float* vqc_b = (const float*)d_in[17];
    const float* fc2_W = (const float*)d_in[18];
    const float* fc2_b = (const float*)d_in[19];
    float* out = (float*)d_out;

    char* p = (char*)d_ws;
    short* Qb   = (short*)p;  p += (size_t)2048 * 768 * 2;
    short* Kfb  = (short*)p;  p += (size_t)2048 * 768 * 2;
    short* Vfb  = (short*)p;  p += (size_t)2048 * 768 * 2;
    float* x2   = (float*)p;  p += (size_t)2048 * 768 * 4;
    float* esb  = (float*)p;  p += (size_t)49152 * 4;
    float* rsb  = (float*)p;  p += (size_t)49152 * 4;
    float* bqkv = (float*)p;  p += 2304 * 4;
    short* actb = (short*)p;  p += (size_t)2048 * 768 * 2;
    short* g    = (short*)p;  p += (size_t)2048 * 3072 * 2;
    short* Avqc = (short*)p;  p += (size_t)8192 * 768 * 2;
    short* partb = (short*)p; p += (size_t)4 * 2048 * 768 * 2;   // 12.6 MB split-K / attn partials
    short* wreg = (short*)p;  p += (size_t)5900544 * 2;
    short* Wqkvb = wreg;
    short* Wob   = wreg + 1769472;
    short* fc1b  = wreg + 2359296;
    short* vqcb  = wreg + 2951424;
    short* fc2b  = wreg + 3541248;

    dim3 blk(256);
    const size_t SP = (size_t)2048 * 768;

    // 0. preamble: ln1 + bias concat + weight conversion (one grid)
    preamble<<<7812, blk, 0, stream>>>(Wq, Wk, Wv, Wo, fc1_W, vqc_W, fc2_W, wreg,
                                       bq, bk, bv, bqkv, x, ln1_w, ln1_b, actb);
    // 1. fused QKV projection (direct, dbuf, 576 blocks)
    gemm_bf16<3, 64><<<dim3(18, 32, 1), blk, 0, stream>>>(actb, 768, Wqkvb, 768, bqkv,
                                                          Qb, 768, 0, Kfb, Vfb, 2304, 768, 0);
    // 2. MFMA attention, KV-split x2 (768 blocks = 3/CU), inline k-norms
    attn_mfma<<<dim3(16, 12, 4), blk, 0, stream>>>(Qb, Kfb, Vfb, partb, esb, rsb);
    // 3. combine + normalize + blend -> vals (actb)
    attn_reduce<<<2048, blk, 0, stream>>>(partb, esb, rsb, pond, actb);
    // 4. Wo split-K x4 (768 blocks = 3/CU)
    gemm_bf16<5, 64><<<dim3(6, 32, 4), blk, 0, stream>>>(actb, 768, Wob, 768, nullptr,
                                                         partb, 768, SP,
                                                         nullptr, nullptr, 768, 192, 0);
    // 5. reduce + bo + residual(x) -> x2 fp32, fused ln2 -> actb
    reduce_wo_ln<<<2048, blk, 0, stream>>>(partb, bo, x, ln2_w, ln2_b, x2, actb);
    // 6. fc1 split-K x4, cols 0..767 only (768 blocks = 3/CU exact)
    gemm_bf16<5, 64><<<dim3(6, 32, 4), blk, 0, stream>>>(actb, 768, fc1b, 768, nullptr,
                                                         partb, 768, SP,
                                                         nullptr, nullptr, 768, 192, 0);
    // 7. reduce + bias + cols 768..770 dots + expand -> Avqc [8192][768]
    reduce_fc1_expand<<<2048, blk, 0, stream>>>(partb, fc1_b, actb, fc1b + 768 * 768, Avqc);
    // 8. vqc (direct) + bias + gelu + transpose scatter (768 blocks = 3/CU)
    gemm_bf16<2, 64><<<dim3(6, 128, 1), blk, 0, stream>>>(Avqc, 768, vqcb, 768, vqc_b,
                                                          g, 3072, 0, nullptr, nullptr, 768, 768, 1);
    // 9. fc2 split-K x4 (768 blocks = 3/CU)
    gemm_bf16<5, 64><<<dim3(6, 32, 4), blk, 0, stream>>>(g, 3072, fc2b, 3072, nullptr,
                                                         partb, 768, SP,
                                                         nullptr, nullptr, 768, 768, 0);
    // 10. reduce + bias + residual(x2) -> out fp32
    reduce_fc2<<<1536, blk, 0, stream>>>(partb, fc2_b, x2, out);
}

// Round 13
// 250.691 us; speedup vs baseline: 1.1649x; 1.0284x over previous
//
#include <hip/hip_runtime.h>
#include <math.h>

#define E_DIM 768
#define S_LEN 1024
#define B_SZ 2
#define H_CNT 12
#define D_HEAD 64
#define M_DIM 768
#define Q_STRIDE 4
#define N_FC1 771            // only M+Q-1 columns of fc1 are consumed

typedef __attribute__((ext_vector_type(8))) short bf16x8;
typedef __attribute__((ext_vector_type(4))) float f32x4;

#define AS1 __attribute__((address_space(1)))
#define AS3 __attribute__((address_space(3)))

__device__ __forceinline__ void gld_lds16(void* lds, const void* g) {
    __builtin_amdgcn_global_load_lds((const AS1 void*)g, (AS3 void*)lds, 16, 0, 0);
}

__device__ __forceinline__ short f2bf(float f) {
    unsigned u = __float_as_uint(f);
    unsigned r = (u + 0x7fffu + ((u >> 16) & 1u)) >> 16;
    return (short)r;
}

__device__ __forceinline__ float bf2f(short s) {
    return __uint_as_float(((unsigned)(unsigned short)s) << 16);
}

// ---------------- block reduction helper (256 threads, 4 waves) ------------

__device__ __forceinline__ float block_reduce_sum(float v, volatile float* red) {
#pragma unroll
    for (int off = 32; off > 0; off >>= 1) v += __shfl_xor(v, off);
    __syncthreads();
    if ((threadIdx.x & 63) == 0) red[threadIdx.x >> 6] = v;
    __syncthreads();
    return red[0] + red[1] + red[2] + red[3];
}

// ------------- preamble: ln1 + bias concat + weight conversion, one grid ---

__global__ __launch_bounds__(256) void preamble(
        const float* __restrict__ Wq, const float* __restrict__ Wk,
        const float* __restrict__ Wv, const float* __restrict__ Wo,
        const float* __restrict__ fc1W, const float* __restrict__ vqcW,
        const float* __restrict__ fc2W, short* __restrict__ dst,
        const float* __restrict__ bq, const float* __restrict__ bk,
        const float* __restrict__ bv, float* __restrict__ bqkv,
        const float* __restrict__ x, const float* __restrict__ ln1_w,
        const float* __restrict__ ln1_b, short* __restrict__ actb) {
    __shared__ float red[4];
    int tid = threadIdx.x;
    if (blockIdx.x < 2048) {          // ln1
        int row = blockIdx.x;
        const float* xr = x + (size_t)row * E_DIM;
        float v0 = xr[tid], v1 = xr[tid + 256], v2 = xr[tid + 512];
        float s = block_reduce_sum(v0 + v1 + v2, red);
        float mu = s * (1.0f / E_DIM);
        float d0 = v0 - mu, d1 = v1 - mu, d2 = v2 - mu;
        float var = block_reduce_sum(d0 * d0 + d1 * d1 + d2 * d2, red) * (1.0f / E_DIM);
        float rs = rsqrtf(var + 1e-5f);
        short* orow = actb + (size_t)row * E_DIM;
        orow[tid]       = f2bf(d0 * rs * ln1_w[tid]       + ln1_b[tid]);
        orow[tid + 256] = f2bf(d1 * rs * ln1_w[tid + 256] + ln1_b[tid + 256]);
        orow[tid + 512] = f2bf(d2 * rs * ln1_w[tid + 512] + ln1_b[tid + 512]);
        return;
    }
    if (blockIdx.x == 2048) {         // bias concat
#pragma unroll
        for (int u = 0; u < 9; u++) {
            int i = tid + u * 256;
            float v = (i < 768) ? bq[i] : (i < 1536) ? bk[i - 768] : bv[i - 1536];
            bqkv[i] = v;
        }
        return;
    }
    int t = (blockIdx.x - 2049) * 256 + tid;      // float4 index
    if (t >= 1475136) return;                     // 5900544 / 4
    int e = t * 4;
    const float* src; int off;
    if      (e < 589824)  { src = Wq;   off = e; }
    else if (e < 1179648) { src = Wk;   off = e - 589824; }
    else if (e < 1769472) { src = Wv;   off = e - 1179648; }
    else if (e < 2359296) { src = Wo;   off = e - 1769472; }
    else if (e < 2951424) { src = fc1W; off = e - 2359296; }
    else if (e < 3541248) { src = vqcW; off = e - 2951424; }
    else                  { src = fc2W; off = e - 3541248; }
    float4 v = *(const float4*)(src + off);
    short4 o = make_short4(f2bf(v.x), f2bf(v.y), f2bf(v.z), f2bf(v.w));
    *(short4*)(dst + e) = o;
}

// ---------------- bf16 MFMA NT GEMM (BK=64, double-buffered, MR-templated) -
// MR x 128 tile, BK=64 (two MRx32 sub-slabs), double-buffered (one barrier
// per iteration). LDS 48 KB at MR=64 -> 3 blocks/CU, matching 768-block
// balanced grids (R10). R5/R6 lesson: runtime-branch epilogues flip the
// allocator into a 68-VGPR accumulator-spill regime; keep OUTMODE a
// template + launch_bounds(256,2). XOR k-slot swizzle -> 2-way alias (free).
// OUTMODE: 2 = bias+GELU+bf16 transpose-scatter (vqc); 3 = QKV split;
//          5 = bf16 partial (no bias) at outp + z*spitch.

template <int OUTMODE, int MR>
__global__ __launch_bounds__(256, 2) void gemm_bf16(
        const short* __restrict__ A, int lda,
        const short* __restrict__ W, int ldw,
        const float* __restrict__ bias,
        void* __restrict__ outp, int ldo, size_t spitch,
        short* __restrict__ Kfp, short* __restrict__ Vfp,
        int N, int klen, int dogelu) {
    constexpr int MI = MR / 32;
    constexpr int AH = MR * 32;
    constexpr int NA = MR / 64;
    constexpr int ASL = 2 * AH;
    __shared__ short At[2 * ASL];
    __shared__ short Bt[2 * 8192];
    const int tid = threadIdx.x;
    const int lane = tid & 63;
    const int wave = tid >> 6;
    const int wr = (wave >> 1) * (MI * 16);
    const int wc = (wave & 1) * 64;
    const int ml = lane & 15;
    const int kq = lane >> 4;
    const int row0 = blockIdx.y * MR;
    const int col0 = blockIdx.x * 128;
    const int kbase = blockIdx.z * klen;

    const short* Ag[NA]; int aoff[NA];
#pragma unroll
    for (int u = 0; u < NA; u++) {
        int c = tid + u * 256;
        int am = c >> 2, ak = ((c & 3) ^ ((am >> 1) & 3)) * 8;
        Ag[u] = A + (size_t)(row0 + am) * lda + ak + kbase;
        aoff[u] = c * 8;
    }
    const int c0 = tid, c1 = tid + 256;
    const int bm0 = c0 >> 2, bk0 = (((c0 & 3) ^ ((bm0 >> 1) & 3))) * 8;
    const int bm1 = c1 >> 2, bk1 = (((c1 & 3) ^ ((bm1 >> 1) & 3))) * 8;
    int wrow0 = col0 + bm0; if (wrow0 > N - 1) wrow0 = N - 1;
    int wrow1 = col0 + bm1; if (wrow1 > N - 1) wrow1 = N - 1;
    const short* Wg0 = W + (size_t)wrow0 * ldw + bk0 + kbase;
    const short* Wg1 = W + (size_t)wrow1 * ldw + bk1 + kbase;

    const int kxor = (kq ^ ((ml >> 1) & 3)) * 8;

    f32x4 acc[MI][4];
#pragma unroll
    for (int i = 0; i < MI; i++)
#pragma unroll
        for (int j = 0; j < 4; j++) acc[i][j] = {0.f, 0.f, 0.f, 0.f};

    auto stage = [&](int buf, int k0) {
        short* Ab = At + buf * ASL;
        short* Bb = Bt + buf * 8192;
#pragma unroll
        for (int u = 0; u < NA; u++) {
            gld_lds16(Ab + aoff[u], Ag[u] + k0);
            gld_lds16(Ab + AH + aoff[u], Ag[u] + k0 + 32);
        }
        gld_lds16(Bb + c0 * 8, Wg0 + k0);
        gld_lds16(Bb + c1 * 8, Wg1 + k0);
        gld_lds16(Bb + 4096 + c0 * 8, Wg0 + k0 + 32);
        gld_lds16(Bb + 4096 + c1 * 8, Wg1 + k0 + 32);
    };

    stage(0, 0);
    int cur = 0;
    for (int k0 = 0; k0 < klen; k0 += 64) {
        __syncthreads();
        if (k0 + 64 < klen) stage(cur ^ 1, k0 + 64);
        const short* Ac = At + cur * ASL;
        const short* Bc = Bt + cur * 8192;
#pragma unroll
        for (int half = 0; half < 2; half++) {
            const short* Ah = Ac + half * AH;
            const short* Bh = Bc + half * 4096;
            bf16x8 af[MI], bfr[4];
#pragma unroll
            for (int i = 0; i < MI; i++)
                af[i] = *(const bf16x8*)&Ah[(wr + i * 16 + ml) * 32 + kxor];
#pragma unroll
            for (int j = 0; j < 4; j++)
                bfr[j] = *(const bf16x8*)&Bh[(wc + j * 16 + ml) * 32 + kxor];
#pragma unroll
            for (int i = 0; i < MI; i++)
#pragma unroll
                for (int j = 0; j < 4; j++)
                    acc[i][j] = __builtin_amdgcn_mfma_f32_16x16x32_bf16(af[i], bfr[j], acc[i][j], 0, 0, 0);
        }
        cur ^= 1;
    }

    // epilogue: C/D layout col = lane&15, row = (lane>>4)*4 + reg
#pragma unroll
    for (int i = 0; i < MI; i++) {
#pragma unroll
        for (int j = 0; j < 4; j++) {
#pragma unroll
            for (int rr = 0; rr < 4; rr++) {
                int r = row0 + wr + i * 16 + kq * 4 + rr;
                int c = col0 + wc + j * 16 + ml;
                if (c < N) {
                    float v = acc[i][j][rr];
                    if (OUTMODE < 4) v += bias[c];
                    if (OUTMODE == 2 && dogelu)
                        v = 0.5f * v * (1.0f + erff(v * 0.70710678118654752f));
                    if (OUTMODE == 2) {
                        ((short*)outp)[(size_t)(r >> 2) * ldo + c * 4 + (r & 3)] = f2bf(v);
                    } else if (OUTMODE == 5) {
                        ((short*)outp)[blockIdx.z * spitch + (size_t)r * ldo + c] = f2bf(v);
                    } else if (OUTMODE == 3) {
                        int s = r & 1023, bb = r >> 10;
                        if (c < 768) {
                            ((short*)outp)[(size_t)r * 768 + c] = f2bf(v);
                        } else if (c < 1536) {
                            int df = c - 768; int hh = df >> 6, d = df & 63;
                            int bh2 = bb * 12 + hh;
                            size_t idx = ((size_t)(bh2 * 64 + (s >> 4)) * 2 + (d >> 5)) * 512
                                       + (size_t)((d >> 3) & 3) * 128 + (size_t)(s & 15) * 8 + (d & 7);
                            Kfp[idx] = f2bf(v);
                        } else {
                            int df = c - 1536; int hh = df >> 6, d = df & 63;
                            int bh2 = bb * 12 + hh;
                            size_t idx = ((size_t)(bh2 * 32 + (s >> 5))) * 2048
                                       + (size_t)(d >> 4) * 512 + (size_t)((s >> 3) & 3) * 128
                                       + (size_t)(d & 15) * 8 + (s & 7);
                            Vfp[idx] = f2bf(v);
                        }
                    }
                }
            }
        }
    }
}

// ---------------- split-K reduce kernels -----------------------------------

// Wo partials (4, bf16) + bo + residual x -> x2 fp32, then LN(ln2) -> y bf16
__global__ __launch_bounds__(256) void reduce_wo_ln(
        const short* __restrict__ part, const float* __restrict__ bo,
        const float* __restrict__ x, const float* __restrict__ w,
        const float* __restrict__ bvec, float* __restrict__ x2,
        short* __restrict__ y) {
    __shared__ float red[4];
    int row = blockIdx.x, tid = threadIdx.x;
    const size_t SP = (size_t)2048 * 768;
    const short* pr = part + (size_t)row * 768;
    const float* xr = x + (size_t)row * 768;
    float* x2r = x2 + (size_t)row * 768;
    float v[3];
#pragma unroll
    for (int u = 0; u < 3; u++) {
        int c = tid + u * 256;
        float s = bo[c] + xr[c];
#pragma unroll
        for (int z = 0; z < 4; z++) s += bf2f(pr[z * SP + c]);
        v[u] = s; x2r[c] = s;
    }
    float s = block_reduce_sum(v[0] + v[1] + v[2], red);
    float mu = s * (1.0f / 768.f);
    float d0 = v[0] - mu, d1 = v[1] - mu, d2 = v[2] - mu;
    float var = block_reduce_sum(d0 * d0 + d1 * d1 + d2 * d2, red) * (1.0f / 768.f);
    float rs = rsqrtf(var + 1e-5f);
    short* orow = y + (size_t)row * 768;
    orow[tid]       = f2bf(d0 * rs * w[tid]       + bvec[tid]);
    orow[tid + 256] = f2bf(d1 * rs * w[tid + 256] + bvec[tid + 256]);
    orow[tid + 512] = f2bf(d2 * rs * w[tid + 512] + bvec[tid + 512]);
}

// fc1 partials (4, bf16 [2048][768], cols 0..767) + bias -> expanded slices.
// Cols 768..770 computed here as block-reduced dots y[r].fc1_W[768+k] so the
// fc1 GEMM runs an exact 768-block grid. Avqc[(r*4+q)][m] = h1[r][m+q].
__global__ __launch_bounds__(256) void reduce_fc1_expand(
        const short* __restrict__ part, const float* __restrict__ b,
        const short* __restrict__ y, const short* __restrict__ w768,
        short* __restrict__ Avqc) {
    __shared__ float row[772];
    __shared__ float red[4];
    int r = blockIdx.x, tid = threadIdx.x;
    const size_t SP = (size_t)2048 * 768;
    const short* pr = part + (size_t)r * 768;
#pragma unroll
    for (int u = 0; u < 3; u++) {
        int c = tid + u * 256;
        float s = b[c];
#pragma unroll
        for (int z = 0; z < 4; z++) s += bf2f(pr[z * SP + c]);
        row[c] = s;
    }
    const short* yr = y + (size_t)r * 768;
    float y0 = bf2f(yr[tid]), y1 = bf2f(yr[tid + 256]), y2 = bf2f(yr[tid + 512]);
#pragma unroll
    for (int k = 0; k < 3; k++) {
        const short* wk = w768 + k * 768;
        float s = y0 * bf2f(wk[tid]) + y1 * bf2f(wk[tid + 256]) + y2 * bf2f(wk[tid + 512]);
        s = block_reduce_sum(s, red);
        if (tid == 0) row[768 + k] = s + b[768 + k];
    }
    __syncthreads();
#pragma unroll
    for (int q = 0; q < 4; q++) {
        short* orow = Avqc + (size_t)(r * 4 + q) * 768;
#pragma unroll
        for (int u = 0; u < 3; u++) {
            int m = tid + u * 256;
            orow[m] = f2bf(row[m + q]);
        }
    }
}

// fc2 partials (4, bf16) + bias + residual x2 -> out fp32
__global__ __launch_bounds__(256) void reduce_fc2(
        const short* __restrict__ part, const float* __restrict__ b,
        const float* __restrict__ x2, float* __restrict__ out) {
    int t = blockIdx.x * 256 + threadIdx.x;
    int row = t / 192;
    int c = (t - row * 192) * 4;
    size_t off = (size_t)row * 768 + c;
    const size_t SP = (size_t)2048 * 768;
    float4 bb = *(const float4*)(b + c);
    float4 xx = *(const float4*)(x2 + off);
    float o0 = bb.x + xx.x, o1 = bb.y + xx.y, o2 = bb.z + xx.z, o3 = bb.w + xx.w;
#pragma unroll
    for (int z = 0; z < 4; z++) {
        short4 v = *(const short4*)(part + z * SP + off);
        o0 += bf2f(v.x); o1 += bf2f(v.y); o2 += bf2f(v.z); o3 += bf2f(v.w);
    }
    float4 o = make_float4(o0, o1, o2, o3);
    *(float4*)(out + off) = o;
}

// ---------------- MFMA fused attention, INTRA-BLOCK KV-split ---------------
// grid (32, 12, 2) = 768 blocks (3/CU exact). Each block: 32 q-rows, one
// head. Wave (wp,wq): wp = KV half (tiles wp*8..wp*8+7), wq = q sub-tile
// (rows qt2*32 + wq*16 ..+15). Both halves' tiles staged per iteration
// (32 KB); 8 iterations (half the barriers of R12). No-max formulation ->
// cross-half combine is linear, done in LDS (overlaying the dead K-tile
// buffer) — no global partials, no second launch, output written normalized.
// Inline k-norms from the already-loaded B-frags (2 shuffles). Pe/Pr are
// per-wave LDS -> no barrier between P write and read.

__global__ __launch_bounds__(256) void attn_mfma(
        const short* __restrict__ Qb,    // [2048][768] bf16
        const short* __restrict__ Kf,    // frag-major
        const short* __restrict__ Vf,    // frag-major
        const float* __restrict__ pond,
        short* __restrict__ vals) {      // [2048][768] bf16
    __shared__ __align__(16) short Kt[2 * 4096];   // [wp][tile]; reused as combine buf
    __shared__ __align__(16) short Vt[2 * 4096];
    __shared__ float qn_l[4][16];
    __shared__ float is_l[4][16];
    __shared__ float esx[2][16], rsx[2][16];
    __shared__ __align__(16) short Pe[4 * 16 * 72];
    __shared__ __align__(16) short Pr[4 * 16 * 72];

    const int tid = threadIdx.x;
    const int lane = tid & 63;
    const int wave = tid >> 6;
    const int wq = wave & 1;       // q sub-tile
    const int wp = wave >> 1;      // KV half
    const int ml = lane & 15;
    const int kq = lane >> 4;
    const int qt2 = blockIdx.x, h = blockIdx.y, b = blockIdx.z;
    const int bh = b * H_CNT + h;

    const int qrow = b * S_LEN + qt2 * 32 + wq * 16 + ml;
    const short* qp = Qb + (size_t)qrow * 768 + h * 64 + kq * 8;
    bf16x8 aq0 = *(const bf16x8*)qp;
    bf16x8 aq1 = *(const bf16x8*)(qp + 32);

    float qn_part = 0.f;
#pragma unroll
    for (int e = 0; e < 8; e++) {
        float v0 = bf2f(aq0[e]), v1 = bf2f(aq1[e]);
        qn_part += v0 * v0 + v1 * v1;
    }
    qn_part += __shfl_xor(qn_part, 16);
    qn_part += __shfl_xor(qn_part, 32);
    if (kq == 0) {
        qn_l[wave][ml] = qn_part;
        float sig = fminf(fmaxf(qn_part, 1e-8f), 1e4f);
        is_l[wave][ml] = 1.0f / sig;
    }
    __syncthreads();

    float qn_r[4], is_r[4];
#pragma unroll
    for (int r = 0; r < 4; r++) {
        qn_r[r] = qn_l[wave][kq * 4 + r];
        is_r[r] = is_l[wave][kq * 4 + r];
    }

    f32x4 Oe[4], Or[4];
#pragma unroll
    for (int dt = 0; dt < 4; dt++) { Oe[dt] = {0.f,0.f,0.f,0.f}; Or[dt] = {0.f,0.f,0.f,0.f}; }
    float es_p[4] = {0.f,0.f,0.f,0.f}, rs_p[4] = {0.f,0.f,0.f,0.f};

    const short* KfB = Kf + (size_t)bh * 65536;
    const short* VfB = Vf + (size_t)bh * 65536;
    short* PeW = Pe + wave * 1152;
    short* PrW = Pr + wave * 1152;
    const short* KtW = Kt + wp * 4096;
    const short* VtW = Vt + wp * 4096;

    for (int it = 0; it < 8; it++) {
        __syncthreads();   // all waves done reading prior tiles
        {
            const short* sk0 = KfB + it * 4096 + tid * 8;
            gld_lds16(Kt + tid * 8, sk0);
            gld_lds16(Kt + 2048 + tid * 8, sk0 + 2048);
            const short* sk1 = KfB + (it + 8) * 4096 + tid * 8;
            gld_lds16(Kt + 4096 + tid * 8, sk1);
            gld_lds16(Kt + 6144 + tid * 8, sk1 + 2048);
            const short* sv0 = VfB + it * 4096 + tid * 8;
            gld_lds16(Vt + tid * 8, sv0);
            gld_lds16(Vt + 2048 + tid * 8, sv0 + 2048);
            const short* sv1 = VfB + (it + 8) * 4096 + tid * 8;
            gld_lds16(Vt + 4096 + tid * 8, sv1);
            gld_lds16(Vt + 6144 + tid * 8, sv1 + 2048);
        }
        __syncthreads();   // tiles resident

#pragma unroll
        for (int jtl = 0; jtl < 4; jtl++) {
            bf16x8 bk0 = *(const bf16x8*)&KtW[(jtl * 2 + 0) * 512 + lane * 8];
            bf16x8 bk1 = *(const bf16x8*)&KtW[(jtl * 2 + 1) * 512 + lane * 8];
            // inline k-norm for j = jtl*16 + ml (this wave's tile)
            float knp = 0.f;
#pragma unroll
            for (int e = 0; e < 8; e++) {
                float k0v = bf2f(bk0[e]), k1v = bf2f(bk1[e]);
                knp += k0v * k0v + k1v * k1v;
            }
            knp += __shfl_xor(knp, 16);
            knp += __shfl_xor(knp, 32);
            f32x4 c = {0.f,0.f,0.f,0.f};
            c = __builtin_amdgcn_mfma_f32_16x16x32_bf16(aq0, bk0, c, 0, 0, 0);
            c = __builtin_amdgcn_mfma_f32_16x16x32_bf16(aq1, bk1, c, 0, 0, 0);
#pragma unroll
            for (int r = 0; r < 4; r++) {
                float qk = c[r];
                float e = __expf(qk * 0.125f);
                float tt = (2.f * qk - qn_r[r] - knp) * is_r[r];
                float rb = fminf(__expf(tt), 1.0f);
                es_p[r] += e; rs_p[r] += rb;
                PeW[(kq * 4 + r) * 72 + jtl * 16 + ml] = f2bf(e);
                PrW[(kq * 4 + r) * 72 + jtl * 16 + ml] = f2bf(rb);
            }
        }
        // (no barrier: P round-trip is wave-local)

#pragma unroll
        for (int jcl = 0; jcl < 2; jcl++) {
            bf16x8 pa_e = *(const bf16x8*)&PeW[ml * 72 + jcl * 32 + kq * 8];
            bf16x8 pa_r = *(const bf16x8*)&PrW[ml * 72 + jcl * 32 + kq * 8];
#pragma unroll
            for (int dt = 0; dt < 4; dt++) {
                bf16x8 bv = *(const bf16x8*)&VtW[(jcl * 4 + dt) * 512 + lane * 8];
                Oe[dt] = __builtin_amdgcn_mfma_f32_16x16x32_bf16(pa_e, bv, Oe[dt], 0, 0, 0);
                Or[dt] = __builtin_amdgcn_mfma_f32_16x16x32_bf16(pa_r, bv, Or[dt], 0, 0, 0);
            }
        }
    }

    // per-wave es/rs row sums
#pragma unroll
    for (int off = 1; off <= 8; off <<= 1) {
#pragma unroll
        for (int r = 0; r < 4; r++) {
            es_p[r] += __shfl_xor(es_p[r], off);
            rs_p[r] += __shfl_xor(rs_p[r], off);
        }
    }

    // cross-half combine in LDS (Kt region is dead after the loop)
    __syncthreads();                     // everyone past the last QK read of Kt
    float* cb = (float*)Kt;              // 16 KB: [wq*64+lane][32]
    if (wp == 1) {
        float* cl = cb + (size_t)(wq * 64 + lane) * 32;
#pragma unroll
        for (int dt = 0; dt < 4; dt++)
#pragma unroll
            for (int r = 0; r < 4; r++) {
                cl[dt * 4 + r] = Oe[dt][r];
                cl[16 + dt * 4 + r] = Or[dt][r];
            }
        if (ml == 0) {
#pragma unroll
            for (int r = 0; r < 4; r++) {
                esx[wq][kq * 4 + r] = es_p[r];
                rsx[wq][kq * 4 + r] = rs_p[r];
            }
        }
    }
    __syncthreads();
    if (wp == 0) {
        float p = pond[0];
        float sv = 1.0f / (1.0f + __expf(-p));
        float p0 = 1.0f - sv, p1 = sv;
        float blendinv = 1.0f / (p0 + p1 + 1e-7f);
        const float* cl = cb + (size_t)(wq * 64 + lane) * 32;
        float we[4], wr[4];
#pragma unroll
        for (int r = 0; r < 4; r++) {
            float es = es_p[r] + esx[wq][kq * 4 + r];
            float rs = rs_p[r] + rsx[wq][kq * 4 + r];
            we[r] = p0 * blendinv / es;
            wr[r] = p1 * blendinv / fmaxf(rs, 1e-8f);
        }
#pragma unroll
        for (int dt = 0; dt < 4; dt++) {
#pragma unroll
            for (int r = 0; r < 4; r++) {
                float oe = Oe[dt][r] + cl[dt * 4 + r];
                float orr = Or[dt][r] + cl[16 + dt * 4 + r];
                float v = oe * we[r] + orr * wr[r];
                int token = b * S_LEN + qt2 * 32 + wq * 16 + kq * 4 + r;
                vals[(size_t)token * 768 + h * 64 + dt * 16 + ml] = f2bf(v);
            }
        }
    }
}

// ---------------- launcher -------------------------------------------------

extern "C" void kernel_launch(void* const* d_in, const int* in_sizes, int n_in,
                              void* d_out, int out_size, void* d_ws, size_t ws_size,
                              hipStream_t stream) {
    const float* x     = (const float*)d_in[0];
    const float* ln1_w = (const float*)d_in[1];
    const float* ln1_b = (const float*)d_in[2];
    const float* Wq    = (const float*)d_in[3];
    const float* bq    = (const float*)d_in[4];
    const float* Wk    = (const float*)d_in[5];
    const float* bk    = (const float*)d_in[6];
    const float* Wv    = (const float*)d_in[7];
    const float* bv    = (const float*)d_in[8];
    const float* Wo    = (const float*)d_in[9];
    const float* bo    = (const float*)d_in[10];
    const float* pond  = (const float*)d_in[11];
    const float* ln2_w = (const float*)d_in[12];
    const float* ln2_b = (const float*)d_in[13];
    const float* fc1_W = (const float*)d_in[14];
    const float* fc1_b = (const float*)d_in[15];
    const float* vqc_W = (const float*)d_in[16];
    const float* vqc_b = (const float*)d_in[17];
    const float* fc2_W = (const float*)d_in[18];
    const float* fc2_b = (const float*)d_in[19];
    float* out = (float*)d_out;

    char* p = (char*)d_ws;
    short* Qb   = (short*)p;  p += (size_t)2048 * 768 * 2;
    short* Kfb  = (short*)p;  p += (size_t)2048 * 768 * 2;
    short* Vfb  = (short*)p;  p += (size_t)2048 * 768 * 2;
    float* x2   = (float*)p;  p += (size_t)2048 * 768 * 4;
    float* bqkv = (float*)p;  p += 2304 * 4;
    short* actb = (short*)p;  p += (size_t)2048 * 768 * 2;
    short* g    = (short*)p;  p += (size_t)2048 * 3072 * 2;
    short* Avqc = (short*)p;  p += (size_t)8192 * 768 * 2;
    short* partb = (short*)p; p += (size_t)4 * 2048 * 768 * 2;   // 12.6 MB split-K partials
    short* wreg = (short*)p;  p += (size_t)5900544 * 2;
    short* Wqkvb = wreg;
    short* Wob   = wreg + 1769472;
    short* fc1b  = wreg + 2359296;
    short* vqcb  = wreg + 2951424;
    short* fc2b  = wreg + 3541248;

    dim3 blk(256);
    const size_t SP = (size_t)2048 * 768;

    // 0. preamble: ln1 + bias concat + weight conversion (one grid)
    preamble<<<7812, blk, 0, stream>>>(Wq, Wk, Wv, Wo, fc1_W, vqc_W, fc2_W, wreg,
                                       bq, bk, bv, bqkv, x, ln1_w, ln1_b, actb);
    // 1. fused QKV projection (direct, dbuf, 576 blocks)
    gemm_bf16<3, 64><<<dim3(18, 32, 1), blk, 0, stream>>>(actb, 768, Wqkvb, 768, bqkv,
                                                          Qb, 768, 0, Kfb, Vfb, 2304, 768, 0);
    // 2. MFMA attention, intra-block KV-split (768 blocks = 3/CU),
    //    direct normalized output -> vals (actb)
    attn_mfma<<<dim3(32, 12, 2), blk, 0, stream>>>(Qb, Kfb, Vfb, pond, actb);
    // 3. Wo split-K x4 (768 blocks = 3/CU)
    gemm_bf16<5, 64><<<dim3(6, 32, 4), blk, 0, stream>>>(actb, 768, Wob, 768, nullptr,
                                                         partb, 768, SP,
                                                         nullptr, nullptr, 768, 192, 0);
    // 4. reduce + bo + residual(x) -> x2 fp32, fused ln2 -> actb
    reduce_wo_ln<<<2048, blk, 0, stream>>>(partb, bo, x, ln2_w, ln2_b, x2, actb);
    // 5. fc1 split-K x4, cols 0..767 only (768 blocks = 3/CU exact)
    gemm_bf16<5, 64><<<dim3(6, 32, 4), blk, 0, stream>>>(actb, 768, fc1b, 768, nullptr,
                                                         partb, 768, SP,
                                                         nullptr, nullptr, 768, 192, 0);
    // 6. reduce + bias + cols 768..770 dots + expand -> Avqc [8192][768]
    reduce_fc1_expand<<<2048, blk, 0, stream>>>(partb, fc1_b, actb, fc1b + 768 * 768, Avqc);
    // 7. vqc (direct) + bias + gelu + transpose scatter (768 blocks = 3/CU)
    gemm_bf16<2, 64><<<dim3(6, 128, 1), blk, 0, stream>>>(Avqc, 768, vqcb, 768, vqc_b,
                                                          g, 3072, 0, nullptr, nullptr, 768, 768, 1);
    // 8. fc2 split-K x4 (768 blocks = 3/CU)
    gemm_bf16<5, 64><<<dim3(6, 32, 4), blk, 0, stream>>>(g, 3072, fc2b, 3072, nullptr,
                                                         partb, 768, SP,
                                                         nullptr, nullptr, 768, 768, 0);
    // 9. reduce + bias + residual(x2) -> out fp32
    reduce_fc2<<<1536, blk, 0, stream>>>(partb, fc2_b, x2, out);
}